// Round 1
// baseline (1196.078 us; speedup 1.0000x reference)
//
#include <hip/hip_runtime.h>
#include <math.h>

#define DIMC 256
#define CO   516
#define NB   32
#define NH   64
#define NW   64
#define NPIX (NB*NH*NW)   // 131072
#define PITCH 264         // k_final LDS row pitch in shorts (256 + 8 pad)
#define CP    76          // conv LDS pitch (floats): %4==0, 4*CP%32!=0
#define CROWS 72          // 64 + 2*4 halo

typedef short short8 __attribute__((ext_vector_type(8)));
typedef float floatx4 __attribute__((ext_vector_type(4)));
typedef unsigned short us4 __attribute__((ext_vector_type(4)));

__device__ __forceinline__ float gelu_f(float x) {
    return 0.5f * x * (1.0f + erff(x * 0.7071067811865476f));
}
__device__ __forceinline__ float clip100(float v) {
    return fminf(100.f, fmaxf(-100.f, v));
}
// round-to-nearest-even split of fp32 into bf16 hi + bf16 lo (x ~= hi+lo)
__device__ __forceinline__ void split2(float x, unsigned short& h, unsigned short& l) {
    unsigned int xb = __float_as_uint(x);
    unsigned int hb = (xb + 0x7fffu + ((xb >> 16) & 1u)) & 0xffff0000u;
    h = (unsigned short)(hb >> 16);
    float r = x - __uint_as_float(hb);
    unsigned int rb = __float_as_uint(r);
    l = (unsigned short)((rb + 0x7fffu + ((rb >> 16) & 1u)) >> 16);
}
__device__ __forceinline__ float bf2f(unsigned short h) {
    return __uint_as_float(((unsigned int)h) << 16);
}

// ---------------------------------------------------------------------------
// Weight prep: transpose + split to bf16 hi/lo. Block 1024..1039 builds the
// 16-column padded gate-weight tile (cols 0..3 = w_init[:,512..515], rest 0).
// ---------------------------------------------------------------------------
__global__ __launch_bounds__(256) void k_prep(const float* __restrict__ w_init,
                                              const float* __restrict__ w_mod,
                                              const float* __restrict__ w_proj,
                                              unsigned short* wiT_h, unsigned short* wiT_l,
                                              unsigned short* wmT_h, unsigned short* wmT_l,
                                              unsigned short* wpT_h, unsigned short* wpT_l,
                                              unsigned short* wgT_h, unsigned short* wgT_l) {
    const int n = blockIdx.x;
    const int k = threadIdx.x;
    unsigned short h, l;
    if (n < 512) {
        split2(w_init[k * CO + n], h, l);
        wiT_h[n * 256 + k] = h; wiT_l[n * 256 + k] = l;
    } else if (n < 768) {
        const int nn = n - 512;
        split2(w_mod[k * 256 + nn], h, l);
        wmT_h[nn * 256 + k] = h; wmT_l[nn * 256 + k] = l;
    } else if (n < 1024) {
        const int nn = n - 768;
        split2(w_proj[k * 256 + nn], h, l);
        wpT_h[nn * 256 + k] = h; wpT_l[nn * 256 + k] = l;
    } else {
        const int nn = n - 1024;          // 0..15, padded gate tile
        const float v = (nn < 4) ? w_init[k * CO + 512 + nn] : 0.f;
        split2(v, h, l);
        wgT_h[nn * 256 + k] = h; wgT_l[nn * 256 + k] = l;
    }
}

// ---------------------------------------------------------------------------
// k_split: split x into bf16 hi/lo, stored in MFMA A-fragment order so
// k_init needs no LDS staging at all.
//   fragment index fidx = tile*32 + im*8 + kki  (tile = 64-pixel group)
//   lane l (0..63) holds 8 shorts = row (tile*64 + im*16 + (l&15)),
//                           k = kki*32 + (l>>4)*8 .. +8
//   xh[(fidx*64 + lane)*8 + j]
// One thread per (fidx,lane): reads 32B of x, writes 16B to xh + 16B to xl.
// ---------------------------------------------------------------------------
__global__ __launch_bounds__(256) void k_split(const float* __restrict__ x,
                                               unsigned short* __restrict__ xh,
                                               unsigned short* __restrict__ xl) {
    const int tid = blockIdx.x * 256 + threadIdx.x;   // == fidx*64 + lane
    const int lane = tid & 63;
    const int fidx = tid >> 6;
    const int tile = fidx >> 5;
    const int im   = (fidx >> 3) & 3;
    const int kki  = fidx & 7;
    const int row  = tile * 64 + im * 16 + (lane & 15);
    const int k0   = kki * 32 + (lane >> 4) * 8;

    const float4 v0 = *(const float4*)&x[(size_t)row * 256 + k0];
    const float4 v1 = *(const float4*)&x[(size_t)row * 256 + k0 + 4];

    short8 hh, ll;
    unsigned short h, l;
    split2(v0.x, h, l); hh[0] = (short)h; ll[0] = (short)l;
    split2(v0.y, h, l); hh[1] = (short)h; ll[1] = (short)l;
    split2(v0.z, h, l); hh[2] = (short)h; ll[2] = (short)l;
    split2(v0.w, h, l); hh[3] = (short)h; ll[3] = (short)l;
    split2(v1.x, h, l); hh[4] = (short)h; ll[4] = (short)l;
    split2(v1.y, h, l); hh[5] = (short)h; ll[5] = (short)l;
    split2(v1.z, h, l); hh[6] = (short)h; ll[6] = (short)l;
    split2(v1.w, h, l); hh[7] = (short)h; ll[7] = (short)l;

    *(short8*)&xh[(size_t)tid * 8] = hh;
    *(short8*)&xl[(size_t)tid * 8] = ll;
}

// ---------------------------------------------------------------------------
// k_init_mfma v2: LDS-free, barrier-free streaming GEMM.
//   x_proj = x @ w_init + b_init (split-bf16, 3-term MFMA)
//   q (cols 0..255)     -> qout [pix][c]  (aliases d_out)
//   ctx (cols 256..511) -> ctxp PLANAR [b][c][4096]
//   gates (512..515)    -> one padded 16-col MFMA tile per wave (im = wv)
// A-fragments stream directly from xh/xl (fragment-order layout); the 4
// waves of a block read the same 128KB tile back-to-back -> L2 hits.
// ---------------------------------------------------------------------------
__global__ __launch_bounds__(256) void k_init_mfma(const unsigned short* __restrict__ xh,
                                                   const unsigned short* __restrict__ xl,
                                                   const unsigned short* __restrict__ wiT_h,
                                                   const unsigned short* __restrict__ wiT_l,
                                                   const unsigned short* __restrict__ wgT_h,
                                                   const unsigned short* __restrict__ wgT_l,
                                                   const float* __restrict__ b_init,
                                                   float* __restrict__ qout,
                                                   float* __restrict__ ctxp,
                                                   float* __restrict__ gates) {
    const int t = threadIdx.x;
    const int wv = t >> 6, lane = t & 63;
    const int l15 = lane & 15, quad = lane >> 4;
    const long tile = blockIdx.x;
    const long p0 = tile * 64;
    const int bb = (int)(p0 >> 12);
    const int pl = (int)(p0 & 4095);

    // per-lane A-fragment base: fragment (im,kki) lives at +(im*8+kki)*512 shorts
    const unsigned short* axh = xh + ((size_t)tile * 32 * 64 + lane) * 8;
    const unsigned short* axl = xl + ((size_t)tile * 32 * 64 + lane) * 8;

    for (int half = 0; half < 2; ++half) {
        const int c0 = half * 256 + wv * 64;
        floatx4 acc[4][4];
        #pragma unroll
        for (int im = 0; im < 4; ++im)
            #pragma unroll
            for (int in_ = 0; in_ < 4; ++in_)
                acc[im][in_] = (floatx4){0.f, 0.f, 0.f, 0.f};

        for (int kki = 0; kki < 8; ++kki) {
            short8 ah[4], al[4], bh[4], bl[4];
            #pragma unroll
            for (int im = 0; im < 4; ++im) {
                ah[im] = *(const short8*)&axh[(size_t)(im * 8 + kki) * 512];
                al[im] = *(const short8*)&axl[(size_t)(im * 8 + kki) * 512];
            }
            #pragma unroll
            for (int in_ = 0; in_ < 4; ++in_) {
                const int off = (c0 + in_ * 16 + l15) * 256 + kki * 32 + quad * 8;
                bh[in_] = *(const short8*)&wiT_h[off];
                bl[in_] = *(const short8*)&wiT_l[off];
            }
            #pragma unroll
            for (int im = 0; im < 4; ++im)
                #pragma unroll
                for (int in_ = 0; in_ < 4; ++in_) {
                    acc[im][in_] = __builtin_amdgcn_mfma_f32_16x16x32_bf16(ah[im], bh[in_], acc[im][in_], 0, 0, 0);
                    acc[im][in_] = __builtin_amdgcn_mfma_f32_16x16x32_bf16(ah[im], bl[in_], acc[im][in_], 0, 0, 0);
                    acc[im][in_] = __builtin_amdgcn_mfma_f32_16x16x32_bf16(al[im], bh[in_], acc[im][in_], 0, 0, 0);
                }
        }

        if (half == 0) {
            #pragma unroll
            for (int in_ = 0; in_ < 4; ++in_) {
                const int col = wv * 64 + in_ * 16 + l15;
                const float bi = b_init[col];
                #pragma unroll
                for (int im = 0; im < 4; ++im)
                    #pragma unroll
                    for (int r = 0; r < 4; ++r) {
                        const int row = im * 16 + quad * 4 + r;
                        qout[(p0 + row) * 256 + col] = acc[im][in_][r] + bi;
                    }
            }
        } else {
            // planar store: 4 consecutive pixels per float4
            #pragma unroll
            for (int in_ = 0; in_ < 4; ++in_) {
                const int col = wv * 64 + in_ * 16 + l15;     // channel
                const float bi = b_init[256 + col];
                #pragma unroll
                for (int im = 0; im < 4; ++im) {
                    float4 o;
                    o.x = acc[im][in_][0] + bi;
                    o.y = acc[im][in_][1] + bi;
                    o.z = acc[im][in_][2] + bi;
                    o.w = acc[im][in_][3] + bi;
                    *(float4*)&ctxp[((size_t)bb * 256 + col) * 4096 + pl + im * 16 + quad * 4] = o;
                }
            }
        }
    }

    // gates via one padded 16-col MFMA tile: wave wv handles rows im=wv
    {
        floatx4 g = (floatx4){0.f, 0.f, 0.f, 0.f};
        const unsigned short* axh_w = axh + (size_t)wv * 8 * 512;
        const unsigned short* axl_w = axl + (size_t)wv * 8 * 512;
        #pragma unroll
        for (int kki = 0; kki < 8; ++kki) {
            const short8 a_h = *(const short8*)&axh_w[(size_t)kki * 512];
            const short8 a_l = *(const short8*)&axl_w[(size_t)kki * 512];
            const int off = l15 * 256 + kki * 32 + quad * 8;
            const short8 b_h = *(const short8*)&wgT_h[off];
            const short8 b_l = *(const short8*)&wgT_l[off];
            g = __builtin_amdgcn_mfma_f32_16x16x32_bf16(a_h, b_h, g, 0, 0, 0);
            g = __builtin_amdgcn_mfma_f32_16x16x32_bf16(a_h, b_l, g, 0, 0, 0);
            g = __builtin_amdgcn_mfma_f32_16x16x32_bf16(a_l, b_h, g, 0, 0, 0);
        }
        if (l15 < 4) {
            const float bi = b_init[512 + l15];
            #pragma unroll
            for (int r = 0; r < 4; ++r) {
                const int row = wv * 16 + quad * 4 + r;
                gates[(p0 + row) * 4 + l15] = fminf(1.f, fmaxf(-1.f, g[r] + bi));
            }
        }
    }
}

// ---------------------------------------------------------------------------
// conv_level: 4x4 output patch at (ry0,cx0) from LDS plane I (halo 4, pitch CP).
// Weights for this block's channel are uniform -> SGPRs. Returns GELU'd v[16].
// ---------------------------------------------------------------------------
template<int KS>
__device__ __forceinline__ void conv_level(const float* __restrict__ kwp,
                                           const float* __restrict__ I,
                                           int ry0, int cx0, float v[16]) {
    constexpr int P = KS / 2;
    constexpr int RWIN = 4 + 2 * P;
    float wk[KS * KS];
    #pragma unroll
    for (int i = 0; i < KS * KS; ++i) wk[i] = kwp[i * 256];

    float4 rb[RWIN][3];
    #pragma unroll
    for (int r = 0; r < 2 * P; ++r) {
        const int base = (ry0 + r - P + 4) * CP + cx0;
        rb[r][0] = *(const float4*)&I[base];
        rb[r][1] = *(const float4*)&I[base + 4];
        rb[r][2] = *(const float4*)&I[base + 8];
    }
    #pragma unroll
    for (int j = 0; j < 4; ++j) {
        {
            const int r = j + 2 * P;
            const int base = (ry0 + r - P + 4) * CP + cx0;
            rb[r][0] = *(const float4*)&I[base];
            rb[r][1] = *(const float4*)&I[base + 4];
            rb[r][2] = *(const float4*)&I[base + 8];
        }
        float s0 = 0.f, s1 = 0.f, s2 = 0.f, s3 = 0.f;
        #pragma unroll
        for (int dy = 0; dy < KS; ++dy) {
            const float* rw = (const float*)&rb[j + dy][0];   // 12 floats, cols cx0-4..cx0+7
            #pragma unroll
            for (int dx = 0; dx < KS; ++dx) {
                const float wgt = wk[dy * KS + dx];
                s0 += rw[4 - P + 0 + dx] * wgt;
                s1 += rw[4 - P + 1 + dx] * wgt;
                s2 += rw[4 - P + 2 + dx] * wgt;
                s3 += rw[4 - P + 3 + dx] * wgt;
            }
        }
        v[j * 4 + 0] = gelu_f(s0);
        v[j * 4 + 1] = gelu_f(s1);
        v[j * 4 + 2] = gelu_f(s2);
        v[j * 4 + 3] = gelu_f(s3);
    }
}

// ---------------------------------------------------------------------------
// k_conv_fused: one block per (b,c) 64x64 plane. Full conv chain in LDS:
//   t1 = gelu(conv3(t0)); t2 = gelu(conv5(t1)); t3 = gelu(conv7(t2))
//   c_all = t1*g0 + t2*g1 + t3*g2 + tanh(mean(t3))*g3   (mean is in-block!)
// Reads ctxp planar, writes c_allp planar. No intermediate HBM traffic.
// ---------------------------------------------------------------------------
__global__ __launch_bounds__(256) void k_conv_fused(const float* __restrict__ ctxp,
                                                    const float* __restrict__ k0,
                                                    const float* __restrict__ k1,
                                                    const float* __restrict__ k2,
                                                    const float* __restrict__ gates,
                                                    float* __restrict__ c_allp) {
    __shared__ float X[CROWS * CP];
    __shared__ float Y[CROWS * CP];
    const int t = threadIdx.x;
    const int bc = blockIdx.x;            // b*256 + c
    const int b = bc >> 8, c = bc & 255;
    const float* src = ctxp + (size_t)bc * 4096;

    for (int i = t; i < CROWS * CP; i += 256) { X[i] = 0.f; Y[i] = 0.f; }
    __syncthreads();
    #pragma unroll
    for (int i = 0; i < 4; ++i) {
        const int p = i * 1024 + t * 4;
        const float4 vv = *(const float4*)&src[p];
        *(float4*)&X[((p >> 6) + 4) * CP + (p & 63) + 4] = vv;
    }
    __syncthreads();

    const int px = t & 15, py = t >> 4;
    const int cx0 = px * 4, ry0 = py * 4;
    const float* gbase = gates + (size_t)b * 4096 * 4;

    float acc[16], v[16];

    // level 0: 3x3 from X, write t1 -> Y
    conv_level<3>(k0 + c, X, ry0, cx0, v);
    #pragma unroll
    for (int j = 0; j < 4; ++j) {
        *(float4*)&Y[(ry0 + j + 4) * CP + cx0 + 4] = *(float4*)&v[j * 4];
        #pragma unroll
        for (int i2 = 0; i2 < 4; ++i2)
            acc[j * 4 + i2] = v[j * 4 + i2] * gbase[((ry0 + j) * 64 + cx0 + i2) * 4 + 0];
    }
    __syncthreads();

    // level 1: 5x5 from Y, write t2 -> X
    conv_level<5>(k1 + c, Y, ry0, cx0, v);
    #pragma unroll
    for (int j = 0; j < 4; ++j) {
        *(float4*)&X[(ry0 + j + 4) * CP + cx0 + 4] = *(float4*)&v[j * 4];
        #pragma unroll
        for (int i2 = 0; i2 < 4; ++i2)
            acc[j * 4 + i2] += v[j * 4 + i2] * gbase[((ry0 + j) * 64 + cx0 + i2) * 4 + 1];
    }
    __syncthreads();

    // level 2: 7x7 from X, t3 stays in registers
    conv_level<7>(k2 + c, X, ry0, cx0, v);
    float vsum = 0.f;
    #pragma unroll
    for (int j = 0; j < 4; ++j)
        #pragma unroll
        for (int i2 = 0; i2 < 4; ++i2) {
            acc[j * 4 + i2] += v[j * 4 + i2] * gbase[((ry0 + j) * 64 + cx0 + i2) * 4 + 2];
            vsum += v[j * 4 + i2];
        }

    // in-block mean of t3 -> tanh -> gl (X reused as scratch after barrier)
    __syncthreads();
    X[t] = vsum;
    __syncthreads();
    if (t < 64) {
        float s = X[t] + X[t + 64] + X[t + 128] + X[t + 192];
        #pragma unroll
        for (int off = 32; off >= 1; off >>= 1)
            s += __shfl_down(s, off, 64);
        if (t == 0) X[0] = tanhf(s * (1.f / 4096.f));
    }
    __syncthreads();
    const float gl = X[0];

    float* dst = c_allp + (size_t)bc * 4096;
    #pragma unroll
    for (int j = 0; j < 4; ++j) {
        float4 o;
        o.x = acc[j * 4 + 0] + gl * gbase[((ry0 + j) * 64 + cx0 + 0) * 4 + 3];
        o.y = acc[j * 4 + 1] + gl * gbase[((ry0 + j) * 64 + cx0 + 1) * 4 + 3];
        o.z = acc[j * 4 + 2] + gl * gbase[((ry0 + j) * 64 + cx0 + 2) * 4 + 3];
        o.w = acc[j * 4 + 3] + gl * gbase[((ry0 + j) * 64 + cx0 + 3) * 4 + 3];
        *(float4*)&dst[(ry0 + j) * 64 + cx0] = o;
    }
}

// ---------------------------------------------------------------------------
// k_final_mfma: stage c_allp (planar -> LDS transpose, split bf16); GEMM1
// mod = c_all@w_mod; p = clip(q)*clip(mod+b_mod); GEMM2 out = p@w_proj+b_proj.
// qout aliases d_out (holds q on entry).
// ---------------------------------------------------------------------------
__global__ __launch_bounds__(256) void k_final_mfma(float* qout,
                                                    const float* __restrict__ c_allp,
                                                    const unsigned short* __restrict__ wmT_h,
                                                    const unsigned short* __restrict__ wmT_l,
                                                    const unsigned short* __restrict__ wpT_h,
                                                    const unsigned short* __restrict__ wpT_l,
                                                    const float* __restrict__ b_mod,
                                                    const float* __restrict__ b_proj) {
    __shared__ unsigned short Ah[64 * PITCH];
    __shared__ unsigned short Al[64 * PITCH];
    const int t = threadIdx.x;
    const long p0 = (long)blockIdx.x * 64;
    const int b = (int)(p0 >> 12);
    const int pl = (int)(p0 & 4095);

    // transpose-stage: thread t = channel t, 64 consecutive pixels
    {
        const float* src = c_allp + ((size_t)b * 256 + t) * 4096 + pl;
        #pragma unroll
        for (int i = 0; i < 16; ++i) {
            const float4 vv = *(const float4*)&src[i * 4];
            unsigned short h, l;
            split2(vv.x, h, l); Ah[(i*4+0)*PITCH + t] = h; Al[(i*4+0)*PITCH + t] = l;
            split2(vv.y, h, l); Ah[(i*4+1)*PITCH + t] = h; Al[(i*4+1)*PITCH + t] = l;
            split2(vv.z, h, l); Ah[(i*4+2)*PITCH + t] = h; Al[(i*4+2)*PITCH + t] = l;
            split2(vv.w, h, l); Ah[(i*4+3)*PITCH + t] = h; Al[(i*4+3)*PITCH + t] = l;
        }
    }
    __syncthreads();

    const int wv = t >> 6, lane = t & 63;
    const int l15 = lane & 15, quad = lane >> 4;
    const int ncol0 = wv * 64;

    floatx4 acc[4][4];
    #pragma unroll
    for (int im = 0; im < 4; ++im)
        #pragma unroll
        for (int in_ = 0; in_ < 4; ++in_)
            acc[im][in_] = (floatx4){0.f, 0.f, 0.f, 0.f};

    for (int kk = 0; kk < 256; kk += 32) {
        short8 ah[4], al[4], bh[4], bl[4];
        #pragma unroll
        for (int im = 0; im < 4; ++im) {
            const int off = (im * 16 + l15) * PITCH + kk + quad * 8;
            ah[im] = *(const short8*)&Ah[off];
            al[im] = *(const short8*)&Al[off];
        }
        #pragma unroll
        for (int in_ = 0; in_ < 4; ++in_) {
            const int off = (ncol0 + in_ * 16 + l15) * 256 + kk + quad * 8;
            bh[in_] = *(const short8*)&wmT_h[off];
            bl[in_] = *(const short8*)&wmT_l[off];
        }
        #pragma unroll
        for (int im = 0; im < 4; ++im)
            #pragma unroll
            for (int in_ = 0; in_ < 4; ++in_) {
                acc[im][in_] = __builtin_amdgcn_mfma_f32_16x16x32_bf16(ah[im], bh[in_], acc[im][in_], 0, 0, 0);
                acc[im][in_] = __builtin_amdgcn_mfma_f32_16x16x32_bf16(ah[im], bl[in_], acc[im][in_], 0, 0, 0);
                acc[im][in_] = __builtin_amdgcn_mfma_f32_16x16x32_bf16(al[im], bh[in_], acc[im][in_], 0, 0, 0);
            }
    }
    __syncthreads();

    // epilogue1: p = clip(q)*clip(mod + b_mod) -> LDS hi/lo
    #pragma unroll
    for (int in_ = 0; in_ < 4; ++in_) {
        const int col = ncol0 + in_ * 16 + l15;
        const float bm = b_mod[col];
        #pragma unroll
        for (int im = 0; im < 4; ++im)
            #pragma unroll
            for (int r = 0; r < 4; ++r) {
                const int row = im * 16 + quad * 4 + r;
                const float m = clip100(acc[im][in_][r] + bm);
                const float qv = clip100(qout[(p0 + row) * 256 + col]);
                unsigned short h, l;
                split2(qv * m, h, l);
                Ah[row * PITCH + col] = h;
                Al[row * PITCH + col] = l;
            }
    }
    __syncthreads();

    #pragma unroll
    for (int im = 0; im < 4; ++im)
        #pragma unroll
        for (int in_ = 0; in_ < 4; ++in_)
            acc[im][in_] = (floatx4){0.f, 0.f, 0.f, 0.f};

    for (int kk = 0; kk < 256; kk += 32) {
        short8 ah[4], al[4], bh[4], bl[4];
        #pragma unroll
        for (int im = 0; im < 4; ++im) {
            const int off = (im * 16 + l15) * PITCH + kk + quad * 8;
            ah[im] = *(const short8*)&Ah[off];
            al[im] = *(const short8*)&Al[off];
        }
        #pragma unroll
        for (int in_ = 0; in_ < 4; ++in_) {
            const int off = (ncol0 + in_ * 16 + l15) * 256 + kk + quad * 8;
            bh[in_] = *(const short8*)&wpT_h[off];
            bl[in_] = *(const short8*)&wpT_l[off];
        }
        #pragma unroll
        for (int im = 0; im < 4; ++im)
            #pragma unroll
            for (int in_ = 0; in_ < 4; ++in_) {
                acc[im][in_] = __builtin_amdgcn_mfma_f32_16x16x32_bf16(ah[im], bh[in_], acc[im][in_], 0, 0, 0);
                acc[im][in_] = __builtin_amdgcn_mfma_f32_16x16x32_bf16(ah[im], bl[in_], acc[im][in_], 0, 0, 0);
                acc[im][in_] = __builtin_amdgcn_mfma_f32_16x16x32_bf16(al[im], bh[in_], acc[im][in_], 0, 0, 0);
            }
    }

    #pragma unroll
    for (int in_ = 0; in_ < 4; ++in_) {
        const int col = ncol0 + in_ * 16 + l15;
        const float bp = b_proj[col];
        #pragma unroll
        for (int im = 0; im < 4; ++im)
            #pragma unroll
            for (int r = 0; r < 4; ++r) {
                const int row = im * 16 + quad * 4 + r;
                qout[(p0 + row) * 256 + col] = acc[im][in_][r] + bp;
            }
    }
}

// ---------------------------------------------------------------------------
extern "C" void kernel_launch(void* const* d_in, const int* in_sizes, int n_in,
                              void* d_out, int out_size, void* d_ws, size_t ws_size,
                              hipStream_t stream) {
    const float* x      = (const float*)d_in[0];
    const float* w_init = (const float*)d_in[1];
    const float* b_init = (const float*)d_in[2];
    const float* k0     = (const float*)d_in[3];
    const float* k1     = (const float*)d_in[4];
    const float* k2     = (const float*)d_in[5];
    const float* w_mod  = (const float*)d_in[6];
    const float* b_mod  = (const float*)d_in[7];
    const float* w_proj = (const float*)d_in[8];
    const float* b_proj = (const float*)d_in[9];
    float* qout = (float*)d_out;

    float* ws = (float*)d_ws;
    const long NP = (long)NPIX * DIMC;
    float* ctxp    = ws;                          // planar [b][c][4096]
    float* c_allp  = ws + NP;                     // planar [b][c][4096]
    float* gates   = ws + 2 * NP;                 // NPIX*4 floats
    unsigned short* wiT_h = (unsigned short*)(gates + (long)NPIX * 4);
    unsigned short* wiT_l = wiT_h + 512 * 256;
    unsigned short* wmT_h = wiT_l + 512 * 256;
    unsigned short* wmT_l = wmT_h + 256 * 256;
    unsigned short* wpT_h = wmT_l + 256 * 256;
    unsigned short* wpT_l = wpT_h + 256 * 256;
    unsigned short* wgT_h = wpT_l + 256 * 256;
    unsigned short* wgT_l = wgT_h + 16 * 256;

    // xh/xl (fragment-order split of x) alias c_allp: only live before
    // k_conv_fused writes c_allp. 2 * NPIX*256 ushorts == NP floats exactly.
    unsigned short* xh = (unsigned short*)c_allp;
    unsigned short* xl = xh + (size_t)NPIX * 256;

    k_prep<<<1040, 256, 0, stream>>>(w_init, w_mod, w_proj,
                                     wiT_h, wiT_l, wmT_h, wmT_l, wpT_h, wpT_l,
                                     wgT_h, wgT_l);
    k_split<<<NPIX * 32 / 256, 256, 0, stream>>>(x, xh, xl);
    k_init_mfma<<<NPIX / 64, 256, 0, stream>>>(xh, xl, wiT_h, wiT_l,
                                               wgT_h, wgT_l, b_init,
                                               qout, ctxp, gates);
    k_conv_fused<<<NB * 256, 256, 0, stream>>>(ctxp, k0, k1, k2, gates, c_allp);
    k_final_mfma<<<NPIX / 64, 256, 0, stream>>>(qout, c_allp,
                                                wmT_h, wmT_l, wpT_h, wpT_l,
                                                b_mod, b_proj);
}

// Round 2
// 942.295 us; speedup vs baseline: 1.2693x; 1.2693x over previous
//
#include <hip/hip_runtime.h>
#include <math.h>

#define DIMC 256
#define CO   516
#define NB   32
#define NH   64
#define NW   64
#define NPIX (NB*NH*NW)   // 131072
#define PITCH 264         // k_final LDS row pitch in shorts (256 + 8 pad)
#define CP    76          // conv LDS pitch (floats): %4==0, 4*CP%32!=0
#define CROWS 72          // 64 + 2*4 halo

typedef short short8 __attribute__((ext_vector_type(8)));
typedef float floatx4 __attribute__((ext_vector_type(4)));
typedef unsigned short us4 __attribute__((ext_vector_type(4)));

__device__ __forceinline__ float gelu_f(float x) {
    return 0.5f * x * (1.0f + erff(x * 0.7071067811865476f));
}
__device__ __forceinline__ float clip100(float v) {
    return fminf(100.f, fmaxf(-100.f, v));
}
// round-to-nearest-even split of fp32 into bf16 hi + bf16 lo (x ~= hi+lo)
__device__ __forceinline__ void split2(float x, unsigned short& h, unsigned short& l) {
    unsigned int xb = __float_as_uint(x);
    unsigned int hb = (xb + 0x7fffu + ((xb >> 16) & 1u)) & 0xffff0000u;
    h = (unsigned short)(hb >> 16);
    float r = x - __uint_as_float(hb);
    unsigned int rb = __float_as_uint(r);
    l = (unsigned short)((rb + 0x7fffu + ((rb >> 16) & 1u)) >> 16);
}

// ---------------------------------------------------------------------------
// Weight prep -> FRAGMENT-ORDER bf16 hi/lo.
// Fragment layout: frag (g,kki,in_) holds B[k = kki*32+quad*8+j][col = g*64+in_*16+l15]
// at ((fragIdx)*64 + lane)*8 + j, lane = quad*16+l15.
//   wiF: g 0..7 (cols 0..511 of w_init)
//   wmF: g 0..3 (w_mod), wpF: g 0..3 (w_proj)
//   wgF: single 16-col padded tile (cols 0..3 = w_init[:,512..515], rest 0)
// ---------------------------------------------------------------------------
__global__ __launch_bounds__(256) void k_prep(const float* __restrict__ w_init,
                                              const float* __restrict__ w_mod,
                                              const float* __restrict__ w_proj,
                                              unsigned short* wiF_h, unsigned short* wiF_l,
                                              unsigned short* wmF_h, unsigned short* wmF_l,
                                              unsigned short* wpF_h, unsigned short* wpF_l,
                                              unsigned short* wgF_h, unsigned short* wgF_l) {
    const int n = blockIdx.x;
    const int k = threadIdx.x;
    const int kki = k >> 5, quad = (k >> 3) & 3, j = k & 7;
    unsigned short h, l;
    if (n < 1024) {
        const int nn = (n < 512) ? n : (n < 768 ? n - 512 : n - 768);
        const int g = nn >> 6, in_ = (nn >> 4) & 3, l15 = nn & 15;
        const size_t idx = ((size_t)((g * 8 + kki) * 4 + in_) * 64 + quad * 16 + l15) * 8 + j;
        if (n < 512) {
            split2(w_init[k * CO + n], h, l);
            wiF_h[idx] = h; wiF_l[idx] = l;
        } else if (n < 768) {
            split2(w_mod[k * 256 + nn], h, l);
            wmF_h[idx] = h; wmF_l[idx] = l;
        } else {
            split2(w_proj[k * 256 + nn], h, l);
            wpF_h[idx] = h; wpF_l[idx] = l;
        }
    } else {
        const int nn = n - 1024;          // 0..15 = l15 of padded gate tile
        const float v = (nn < 4) ? w_init[k * CO + 512 + nn] : 0.f;
        split2(v, h, l);
        const size_t idx = ((size_t)kki * 64 + quad * 16 + nn) * 8 + j;
        wgF_h[idx] = h; wgF_l[idx] = l;
    }
}

// ---------------------------------------------------------------------------
// k_init_mfma v3: x_proj = x @ w_init + b_init.
//   stage: x (f32) -> split -> fragment-order hi/lo LDS (64KB, lane-linear,
//          conflict-free). A then comes from LDS (short latency), B from
//          L2-hot fragment-order global. K-loop fully unrolled so the
//          scheduler can hoist loads across iterations.
//   q (cols 0..255)     -> qout [pix][c]  (aliases d_out)
//   ctx (cols 256..511) -> ctxp PLANAR [b][c][4096]
//   gates (512..515)    -> padded 16-col MFMA tile per wave
// ---------------------------------------------------------------------------
__global__ __launch_bounds__(256) void k_init_mfma(const float* __restrict__ x,
                                                   const unsigned short* __restrict__ wiF_h,
                                                   const unsigned short* __restrict__ wiF_l,
                                                   const unsigned short* __restrict__ wgF_h,
                                                   const unsigned short* __restrict__ wgF_l,
                                                   const float* __restrict__ b_init,
                                                   float* __restrict__ qout,
                                                   float* __restrict__ ctxp,
                                                   float* __restrict__ gates) {
    __shared__ unsigned short Ah[16384];   // 32 frags * 64 lanes * 8 shorts = 32KB
    __shared__ unsigned short Al[16384];
    const int t = threadIdx.x;
    const int wv = t >> 6, lane = t & 63;
    const int l15 = lane & 15, quad = lane >> 4;
    const long tile = blockIdx.x;
    const long p0 = tile * 64;
    const int bb = (int)(p0 >> 12);
    const int pl = (int)(p0 & 4095);

    // ---- stage: thread (wv,lane) covers row p0 + wv*16 + l15, k = kki*32+quad*8 ----
    {
        const float* xr = x + (size_t)(p0 + wv * 16 + l15) * 256 + quad * 8;
        #pragma unroll
        for (int kki = 0; kki < 8; ++kki) {
            const float4 v0 = *(const float4*)&xr[kki * 32];
            const float4 v1 = *(const float4*)&xr[kki * 32 + 4];
            short8 hh, ll;
            unsigned short h, l;
            split2(v0.x, h, l); hh[0] = (short)h; ll[0] = (short)l;
            split2(v0.y, h, l); hh[1] = (short)h; ll[1] = (short)l;
            split2(v0.z, h, l); hh[2] = (short)h; ll[2] = (short)l;
            split2(v0.w, h, l); hh[3] = (short)h; ll[3] = (short)l;
            split2(v1.x, h, l); hh[4] = (short)h; ll[4] = (short)l;
            split2(v1.y, h, l); hh[5] = (short)h; ll[5] = (short)l;
            split2(v1.z, h, l); hh[6] = (short)h; ll[6] = (short)l;
            split2(v1.w, h, l); hh[7] = (short)h; ll[7] = (short)l;
            const int o = ((wv * 8 + kki) * 64 + lane) * 8;
            *(short8*)&Ah[o] = hh;
            *(short8*)&Al[o] = ll;
        }
    }
    __syncthreads();

    for (int half = 0; half < 2; ++half) {
        const int g = half * 4 + wv;
        const unsigned short* Bh = wiF_h + (size_t)g * 16384;
        const unsigned short* Bl = wiF_l + (size_t)g * 16384;
        floatx4 acc[4][4];
        #pragma unroll
        for (int im = 0; im < 4; ++im)
            #pragma unroll
            for (int in_ = 0; in_ < 4; ++in_)
                acc[im][in_] = (floatx4){0.f, 0.f, 0.f, 0.f};

        #pragma unroll
        for (int kki = 0; kki < 8; ++kki) {
            short8 ah[4], al[4], bh[4], bl[4];
            #pragma unroll
            for (int in_ = 0; in_ < 4; ++in_) {
                const int o = ((kki * 4 + in_) * 64 + lane) * 8;
                bh[in_] = *(const short8*)&Bh[o];
                bl[in_] = *(const short8*)&Bl[o];
            }
            #pragma unroll
            for (int im = 0; im < 4; ++im) {
                const int o = ((im * 8 + kki) * 64 + lane) * 8;
                ah[im] = *(const short8*)&Ah[o];
                al[im] = *(const short8*)&Al[o];
            }
            #pragma unroll
            for (int im = 0; im < 4; ++im)
                #pragma unroll
                for (int in_ = 0; in_ < 4; ++in_) {
                    acc[im][in_] = __builtin_amdgcn_mfma_f32_16x16x32_bf16(ah[im], bh[in_], acc[im][in_], 0, 0, 0);
                    acc[im][in_] = __builtin_amdgcn_mfma_f32_16x16x32_bf16(ah[im], bl[in_], acc[im][in_], 0, 0, 0);
                    acc[im][in_] = __builtin_amdgcn_mfma_f32_16x16x32_bf16(al[im], bh[in_], acc[im][in_], 0, 0, 0);
                }
        }

        if (half == 0) {
            #pragma unroll
            for (int in_ = 0; in_ < 4; ++in_) {
                const int col = wv * 64 + in_ * 16 + l15;
                const float bi = b_init[col];
                #pragma unroll
                for (int im = 0; im < 4; ++im)
                    #pragma unroll
                    for (int r = 0; r < 4; ++r) {
                        const int row = im * 16 + quad * 4 + r;
                        qout[(p0 + row) * 256 + col] = acc[im][in_][r] + bi;
                    }
            }
        } else {
            // planar store: 4 consecutive pixels per float4
            #pragma unroll
            for (int in_ = 0; in_ < 4; ++in_) {
                const int col = wv * 64 + in_ * 16 + l15;     // channel
                const float bi = b_init[256 + col];
                #pragma unroll
                for (int im = 0; im < 4; ++im) {
                    float4 o;
                    o.x = acc[im][in_][0] + bi;
                    o.y = acc[im][in_][1] + bi;
                    o.z = acc[im][in_][2] + bi;
                    o.w = acc[im][in_][3] + bi;
                    *(float4*)&ctxp[((size_t)bb * 256 + col) * 4096 + pl + im * 16 + quad * 4] = o;
                }
            }
        }
    }

    // gates: one padded 16-col MFMA tile; wave wv handles rows im=wv
    {
        floatx4 gacc = (floatx4){0.f, 0.f, 0.f, 0.f};
        #pragma unroll
        for (int kki = 0; kki < 8; ++kki) {
            const int oa = ((wv * 8 + kki) * 64 + lane) * 8;
            const short8 a_h = *(const short8*)&Ah[oa];
            const short8 a_l = *(const short8*)&Al[oa];
            const int ob = (kki * 64 + lane) * 8;
            const short8 b_h = *(const short8*)&wgF_h[ob];
            const short8 b_l = *(const short8*)&wgF_l[ob];
            gacc = __builtin_amdgcn_mfma_f32_16x16x32_bf16(a_h, b_h, gacc, 0, 0, 0);
            gacc = __builtin_amdgcn_mfma_f32_16x16x32_bf16(a_h, b_l, gacc, 0, 0, 0);
            gacc = __builtin_amdgcn_mfma_f32_16x16x32_bf16(a_l, b_h, gacc, 0, 0, 0);
        }
        if (l15 < 4) {
            const float bi = b_init[512 + l15];
            #pragma unroll
            for (int r = 0; r < 4; ++r) {
                const int row = wv * 16 + quad * 4 + r;
                gates[(p0 + row) * 4 + l15] = fminf(1.f, fmaxf(-1.f, gacc[r] + bi));
            }
        }
    }
}

// ---------------------------------------------------------------------------
// conv_level: 4x4 output patch at (ry0,cx0) from LDS plane I (halo 4, pitch CP).
// Weights for this block's channel are uniform -> SGPRs. Returns GELU'd v[16].
// ---------------------------------------------------------------------------
template<int KS>
__device__ __forceinline__ void conv_level(const float* __restrict__ kwp,
                                           const float* __restrict__ I,
                                           int ry0, int cx0, float v[16]) {
    constexpr int P = KS / 2;
    constexpr int RWIN = 4 + 2 * P;
    float wk[KS * KS];
    #pragma unroll
    for (int i = 0; i < KS * KS; ++i) wk[i] = kwp[i * 256];

    float4 rb[RWIN][3];
    #pragma unroll
    for (int r = 0; r < 2 * P; ++r) {
        const int base = (ry0 + r - P + 4) * CP + cx0;
        rb[r][0] = *(const float4*)&I[base];
        rb[r][1] = *(const float4*)&I[base + 4];
        rb[r][2] = *(const float4*)&I[base + 8];
    }
    #pragma unroll
    for (int j = 0; j < 4; ++j) {
        {
            const int r = j + 2 * P;
            const int base = (ry0 + r - P + 4) * CP + cx0;
            rb[r][0] = *(const float4*)&I[base];
            rb[r][1] = *(const float4*)&I[base + 4];
            rb[r][2] = *(const float4*)&I[base + 8];
        }
        float s0 = 0.f, s1 = 0.f, s2 = 0.f, s3 = 0.f;
        #pragma unroll
        for (int dy = 0; dy < KS; ++dy) {
            const float* rw = (const float*)&rb[j + dy][0];   // 12 floats, cols cx0-4..cx0+7
            #pragma unroll
            for (int dx = 0; dx < KS; ++dx) {
                const float wgt = wk[dy * KS + dx];
                s0 += rw[4 - P + 0 + dx] * wgt;
                s1 += rw[4 - P + 1 + dx] * wgt;
                s2 += rw[4 - P + 2 + dx] * wgt;
                s3 += rw[4 - P + 3 + dx] * wgt;
            }
        }
        v[j * 4 + 0] = gelu_f(s0);
        v[j * 4 + 1] = gelu_f(s1);
        v[j * 4 + 2] = gelu_f(s2);
        v[j * 4 + 3] = gelu_f(s3);
    }
}

// ---------------------------------------------------------------------------
// k_conv_fused: one block per (b,c) 64x64 plane. Full conv chain in LDS:
//   t1 = gelu(conv3(t0)); t2 = gelu(conv5(t1)); t3 = gelu(conv7(t2))
//   c_all = t1*g0 + t2*g1 + t3*g2 + tanh(mean(t3))*g3   (mean is in-block!)
// Reads ctxp planar, writes c_allp planar. No intermediate HBM traffic.
// ---------------------------------------------------------------------------
__global__ __launch_bounds__(256) void k_conv_fused(const float* __restrict__ ctxp,
                                                    const float* __restrict__ k0,
                                                    const float* __restrict__ k1,
                                                    const float* __restrict__ k2,
                                                    const float* __restrict__ gates,
                                                    float* __restrict__ c_allp) {
    __shared__ float X[CROWS * CP];
    __shared__ float Y[CROWS * CP];
    const int t = threadIdx.x;
    const int bc = blockIdx.x;            // b*256 + c
    const int b = bc >> 8, c = bc & 255;
    const float* src = ctxp + (size_t)bc * 4096;

    for (int i = t; i < CROWS * CP; i += 256) { X[i] = 0.f; Y[i] = 0.f; }
    __syncthreads();
    #pragma unroll
    for (int i = 0; i < 4; ++i) {
        const int p = i * 1024 + t * 4;
        const float4 vv = *(const float4*)&src[p];
        *(float4*)&X[((p >> 6) + 4) * CP + (p & 63) + 4] = vv;
    }
    __syncthreads();

    const int px = t & 15, py = t >> 4;
    const int cx0 = px * 4, ry0 = py * 4;
    const float* gbase = gates + (size_t)b * 4096 * 4;

    float acc[16], v[16];

    // level 0: 3x3 from X, write t1 -> Y
    conv_level<3>(k0 + c, X, ry0, cx0, v);
    #pragma unroll
    for (int j = 0; j < 4; ++j) {
        *(float4*)&Y[(ry0 + j + 4) * CP + cx0 + 4] = *(float4*)&v[j * 4];
        #pragma unroll
        for (int i2 = 0; i2 < 4; ++i2)
            acc[j * 4 + i2] = v[j * 4 + i2] * gbase[((ry0 + j) * 64 + cx0 + i2) * 4 + 0];
    }
    __syncthreads();

    // level 1: 5x5 from Y, write t2 -> X
    conv_level<5>(k1 + c, Y, ry0, cx0, v);
    #pragma unroll
    for (int j = 0; j < 4; ++j) {
        *(float4*)&X[(ry0 + j + 4) * CP + cx0 + 4] = *(float4*)&v[j * 4];
        #pragma unroll
        for (int i2 = 0; i2 < 4; ++i2)
            acc[j * 4 + i2] += v[j * 4 + i2] * gbase[((ry0 + j) * 64 + cx0 + i2) * 4 + 1];
    }
    __syncthreads();

    // level 2: 7x7 from X, t3 stays in registers
    conv_level<7>(k2 + c, X, ry0, cx0, v);
    float vsum = 0.f;
    #pragma unroll
    for (int j = 0; j < 4; ++j)
        #pragma unroll
        for (int i2 = 0; i2 < 4; ++i2) {
            acc[j * 4 + i2] += v[j * 4 + i2] * gbase[((ry0 + j) * 64 + cx0 + i2) * 4 + 2];
            vsum += v[j * 4 + i2];
        }

    // in-block mean of t3 -> tanh -> gl (X reused as scratch after barrier)
    __syncthreads();
    X[t] = vsum;
    __syncthreads();
    if (t < 64) {
        float s = X[t] + X[t + 64] + X[t + 128] + X[t + 192];
        #pragma unroll
        for (int off = 32; off >= 1; off >>= 1)
            s += __shfl_down(s, off, 64);
        if (t == 0) X[0] = tanhf(s * (1.f / 4096.f));
    }
    __syncthreads();
    const float gl = X[0];

    float* dst = c_allp + (size_t)bc * 4096;
    #pragma unroll
    for (int j = 0; j < 4; ++j) {
        float4 o;
        o.x = acc[j * 4 + 0] + gl * gbase[((ry0 + j) * 64 + cx0 + 0) * 4 + 3];
        o.y = acc[j * 4 + 1] + gl * gbase[((ry0 + j) * 64 + cx0 + 1) * 4 + 3];
        o.z = acc[j * 4 + 2] + gl * gbase[((ry0 + j) * 64 + cx0 + 2) * 4 + 3];
        o.w = acc[j * 4 + 3] + gl * gbase[((ry0 + j) * 64 + cx0 + 3) * 4 + 3];
        *(float4*)&dst[(ry0 + j) * 64 + cx0] = o;
    }
}

// ---------------------------------------------------------------------------
// k_final_mfma: stage c_allp (planar -> LDS transpose, split bf16); GEMM1
// mod = c_all@w_mod; p = clip(q)*clip(mod+b_mod); GEMM2 out = p@w_proj+b_proj.
// qout aliases d_out (holds q on entry). B in fragment order; K-loops unrolled.
// ---------------------------------------------------------------------------
__global__ __launch_bounds__(256) void k_final_mfma(float* qout,
                                                    const float* __restrict__ c_allp,
                                                    const unsigned short* __restrict__ wmF_h,
                                                    const unsigned short* __restrict__ wmF_l,
                                                    const unsigned short* __restrict__ wpF_h,
                                                    const unsigned short* __restrict__ wpF_l,
                                                    const float* __restrict__ b_mod,
                                                    const float* __restrict__ b_proj) {
    __shared__ unsigned short Ah[64 * PITCH];
    __shared__ unsigned short Al[64 * PITCH];
    const int t = threadIdx.x;
    const long p0 = (long)blockIdx.x * 64;
    const int b = (int)(p0 >> 12);
    const int pl = (int)(p0 & 4095);

    // transpose-stage: thread t = channel t, 64 consecutive pixels
    {
        const float* src = c_allp + ((size_t)b * 256 + t) * 4096 + pl;
        #pragma unroll
        for (int i = 0; i < 16; ++i) {
            const float4 vv = *(const float4*)&src[i * 4];
            unsigned short h, l;
            split2(vv.x, h, l); Ah[(i*4+0)*PITCH + t] = h; Al[(i*4+0)*PITCH + t] = l;
            split2(vv.y, h, l); Ah[(i*4+1)*PITCH + t] = h; Al[(i*4+1)*PITCH + t] = l;
            split2(vv.z, h, l); Ah[(i*4+2)*PITCH + t] = h; Al[(i*4+2)*PITCH + t] = l;
            split2(vv.w, h, l); Ah[(i*4+3)*PITCH + t] = h; Al[(i*4+3)*PITCH + t] = l;
        }
    }
    __syncthreads();

    const int wv = t >> 6, lane = t & 63;
    const int l15 = lane & 15, quad = lane >> 4;
    const int ncol0 = wv * 64;
    const unsigned short* BmH = wmF_h + (size_t)wv * 16384;
    const unsigned short* BmL = wmF_l + (size_t)wv * 16384;
    const unsigned short* BpH = wpF_h + (size_t)wv * 16384;
    const unsigned short* BpL = wpF_l + (size_t)wv * 16384;

    floatx4 acc[4][4];
    #pragma unroll
    for (int im = 0; im < 4; ++im)
        #pragma unroll
        for (int in_ = 0; in_ < 4; ++in_)
            acc[im][in_] = (floatx4){0.f, 0.f, 0.f, 0.f};

    #pragma unroll
    for (int kki = 0; kki < 8; ++kki) {
        short8 ah[4], al[4], bh[4], bl[4];
        #pragma unroll
        for (int in_ = 0; in_ < 4; ++in_) {
            const int o = ((kki * 4 + in_) * 64 + lane) * 8;
            bh[in_] = *(const short8*)&BmH[o];
            bl[in_] = *(const short8*)&BmL[o];
        }
        #pragma unroll
        for (int im = 0; im < 4; ++im) {
            const int off = (im * 16 + l15) * PITCH + kki * 32 + quad * 8;
            ah[im] = *(const short8*)&Ah[off];
            al[im] = *(const short8*)&Al[off];
        }
        #pragma unroll
        for (int im = 0; im < 4; ++im)
            #pragma unroll
            for (int in_ = 0; in_ < 4; ++in_) {
                acc[im][in_] = __builtin_amdgcn_mfma_f32_16x16x32_bf16(ah[im], bh[in_], acc[im][in_], 0, 0, 0);
                acc[im][in_] = __builtin_amdgcn_mfma_f32_16x16x32_bf16(ah[im], bl[in_], acc[im][in_], 0, 0, 0);
                acc[im][in_] = __builtin_amdgcn_mfma_f32_16x16x32_bf16(al[im], bh[in_], acc[im][in_], 0, 0, 0);
            }
    }
    __syncthreads();

    // epilogue1: p = clip(q)*clip(mod + b_mod) -> LDS hi/lo
    #pragma unroll
    for (int in_ = 0; in_ < 4; ++in_) {
        const int col = ncol0 + in_ * 16 + l15;
        const float bm = b_mod[col];
        #pragma unroll
        for (int im = 0; im < 4; ++im)
            #pragma unroll
            for (int r = 0; r < 4; ++r) {
                const int row = im * 16 + quad * 4 + r;
                const float m = clip100(acc[im][in_][r] + bm);
                const float qv = clip100(qout[(p0 + row) * 256 + col]);
                unsigned short h, l;
                split2(qv * m, h, l);
                Ah[row * PITCH + col] = h;
                Al[row * PITCH + col] = l;
            }
    }
    __syncthreads();

    #pragma unroll
    for (int im = 0; im < 4; ++im)
        #pragma unroll
        for (int in_ = 0; in_ < 4; ++in_)
            acc[im][in_] = (floatx4){0.f, 0.f, 0.f, 0.f};

    #pragma unroll
    for (int kki = 0; kki < 8; ++kki) {
        short8 ah[4], al[4], bh[4], bl[4];
        #pragma unroll
        for (int in_ = 0; in_ < 4; ++in_) {
            const int o = ((kki * 4 + in_) * 64 + lane) * 8;
            bh[in_] = *(const short8*)&BpH[o];
            bl[in_] = *(const short8*)&BpL[o];
        }
        #pragma unroll
        for (int im = 0; im < 4; ++im) {
            const int off = (im * 16 + l15) * PITCH + kki * 32 + quad * 8;
            ah[im] = *(const short8*)&Ah[off];
            al[im] = *(const short8*)&Al[off];
        }
        #pragma unroll
        for (int im = 0; im < 4; ++im)
            #pragma unroll
            for (int in_ = 0; in_ < 4; ++in_) {
                acc[im][in_] = __builtin_amdgcn_mfma_f32_16x16x32_bf16(ah[im], bh[in_], acc[im][in_], 0, 0, 0);
                acc[im][in_] = __builtin_amdgcn_mfma_f32_16x16x32_bf16(ah[im], bl[in_], acc[im][in_], 0, 0, 0);
                acc[im][in_] = __builtin_amdgcn_mfma_f32_16x16x32_bf16(al[im], bh[in_], acc[im][in_], 0, 0, 0);
            }
    }

    #pragma unroll
    for (int in_ = 0; in_ < 4; ++in_) {
        const int col = ncol0 + in_ * 16 + l15;
        const float bp = b_proj[col];
        #pragma unroll
        for (int im = 0; im < 4; ++im)
            #pragma unroll
            for (int r = 0; r < 4; ++r) {
                const int row = im * 16 + quad * 4 + r;
                qout[(p0 + row) * 256 + col] = acc[im][in_][r] + bp;
            }
    }
}

// ---------------------------------------------------------------------------
extern "C" void kernel_launch(void* const* d_in, const int* in_sizes, int n_in,
                              void* d_out, int out_size, void* d_ws, size_t ws_size,
                              hipStream_t stream) {
    const float* x      = (const float*)d_in[0];
    const float* w_init = (const float*)d_in[1];
    const float* b_init = (const float*)d_in[2];
    const float* k0     = (const float*)d_in[3];
    const float* k1     = (const float*)d_in[4];
    const float* k2     = (const float*)d_in[5];
    const float* w_mod  = (const float*)d_in[6];
    const float* b_mod  = (const float*)d_in[7];
    const float* w_proj = (const float*)d_in[8];
    const float* b_proj = (const float*)d_in[9];
    float* qout = (float*)d_out;

    float* ws = (float*)d_ws;
    const long NP = (long)NPIX * DIMC;
    float* ctxp    = ws;                          // planar [b][c][4096]
    float* c_allp  = ws + NP;                     // planar [b][c][4096]
    float* gates   = ws + 2 * NP;                 // NPIX*4 floats
    unsigned short* wiF_h = (unsigned short*)(gates + (long)NPIX * 4);
    unsigned short* wiF_l = wiF_h + 512 * 256;
    unsigned short* wmF_h = wiF_l + 512 * 256;
    unsigned short* wmF_l = wmF_h + 256 * 256;
    unsigned short* wpF_h = wmF_l + 256 * 256;
    unsigned short* wpF_l = wpF_h + 256 * 256;
    unsigned short* wgF_h = wpF_l + 256 * 256;
    unsigned short* wgF_l = wgF_h + 16 * 256;

    k_prep<<<1040, 256, 0, stream>>>(w_init, w_mod, w_proj,
                                     wiF_h, wiF_l, wmF_h, wmF_l, wpF_h, wpF_l,
                                     wgF_h, wgF_l);
    k_init_mfma<<<NPIX / 64, 256, 0, stream>>>(x, wiF_h, wiF_l,
                                               wgF_h, wgF_l, b_init,
                                               qout, ctxp, gates);
    k_conv_fused<<<NB * 256, 256, 0, stream>>>(ctxp, k0, k1, k2, gates, c_allp);
    k_final_mfma<<<NPIX / 64, 256, 0, stream>>>(qout, c_allp,
                                                wmF_h, wmF_l, wpF_h, wpF_l,
                                                b_mod, b_proj);
}

// Round 4
// 865.962 us; speedup vs baseline: 1.3812x; 1.0881x over previous
//
#include <hip/hip_runtime.h>
#include <math.h>

#define DIMC 256
#define CO   516
#define NB   32
#define NH   64
#define NW   64
#define NPIX (NB*NH*NW)   // 131072
#define PITCH 264         // k_final LDS row pitch in shorts (256 + 8 pad)
#define CP    76          // conv LDS pitch (floats): %4==0; 2*CP%32=24 -> py offsets distinct
#define CROWS 72          // 64 + 2*4 halo

typedef short short8 __attribute__((ext_vector_type(8)));
typedef float floatx4 __attribute__((ext_vector_type(4)));
typedef unsigned short us4 __attribute__((ext_vector_type(4)));

__device__ __forceinline__ float gelu_f(float x) {
    return 0.5f * x * (1.0f + erff(x * 0.7071067811865476f));
}
__device__ __forceinline__ float clip100(float v) {
    return fminf(100.f, fmaxf(-100.f, v));
}
// round-to-nearest-even split of fp32 into bf16 hi + bf16 lo (x ~= hi+lo)
__device__ __forceinline__ void split2(float x, unsigned short& h, unsigned short& l) {
    unsigned int xb = __float_as_uint(x);
    unsigned int hb = (xb + 0x7fffu + ((xb >> 16) & 1u)) & 0xffff0000u;
    h = (unsigned short)(hb >> 16);
    float r = x - __uint_as_float(hb);
    unsigned int rb = __float_as_uint(r);
    l = (unsigned short)((rb + 0x7fffu + ((rb >> 16) & 1u)) >> 16);
}

// ---------------------------------------------------------------------------
// Weight prep -> FRAGMENT-ORDER bf16 hi/lo.
// Fragment layout: frag (g,kki,in_) holds B[k = kki*32+quad*8+j][col = g*64+in_*16+l15]
// at ((fragIdx)*64 + lane)*8 + j, lane = quad*16+l15.
// ---------------------------------------------------------------------------
__global__ __launch_bounds__(256) void k_prep(const float* __restrict__ w_init,
                                              const float* __restrict__ w_mod,
                                              const float* __restrict__ w_proj,
                                              unsigned short* wiF_h, unsigned short* wiF_l,
                                              unsigned short* wmF_h, unsigned short* wmF_l,
                                              unsigned short* wpF_h, unsigned short* wpF_l,
                                              unsigned short* wgF_h, unsigned short* wgF_l) {
    const int n = blockIdx.x;
    const int k = threadIdx.x;
    const int kki = k >> 5, quad = (k >> 3) & 3, j = k & 7;
    unsigned short h, l;
    if (n < 1024) {
        const int nn = (n < 512) ? n : (n < 768 ? n - 512 : n - 768);
        const int g = nn >> 6, in_ = (nn >> 4) & 3, l15 = nn & 15;
        const size_t idx = ((size_t)((g * 8 + kki) * 4 + in_) * 64 + quad * 16 + l15) * 8 + j;
        if (n < 512) {
            split2(w_init[k * CO + n], h, l);
            wiF_h[idx] = h; wiF_l[idx] = l;
        } else if (n < 768) {
            split2(w_mod[k * 256 + nn], h, l);
            wmF_h[idx] = h; wmF_l[idx] = l;
        } else {
            split2(w_proj[k * 256 + nn], h, l);
            wpF_h[idx] = h; wpF_l[idx] = l;
        }
    } else {
        const int nn = n - 1024;          // 0..15 = l15 of padded gate tile
        const float v = (nn < 4) ? w_init[k * CO + 512 + nn] : 0.f;
        split2(v, h, l);
        const size_t idx = ((size_t)kki * 64 + quad * 16 + nn) * 8 + j;
        wgF_h[idx] = h; wgF_l[idx] = l;
    }
}

// ---------------------------------------------------------------------------
// k_init_mfma v4: K-tiled LDS staging (32KB -> up to 5 blocks/CU).
//   phase h: stage x[k in h*128..h*128+128) as fragment-order hi/lo LDS,
//   then MFMA kki = h*4..h*4+3 into persistent accq/accc/gacc.
// ---------------------------------------------------------------------------
__global__ __launch_bounds__(256) void k_init_mfma(const float* __restrict__ x,
                                                   const unsigned short* __restrict__ wiF_h,
                                                   const unsigned short* __restrict__ wiF_l,
                                                   const unsigned short* __restrict__ wgF_h,
                                                   const unsigned short* __restrict__ wgF_l,
                                                   const float* __restrict__ b_init,
                                                   float* __restrict__ qout,
                                                   float* __restrict__ ctxp,
                                                   float* __restrict__ gates) {
    __shared__ unsigned short Ah[8192];   // 16 frags * 64 lanes * 8 shorts = 16KB
    __shared__ unsigned short Al[8192];
    const int t = threadIdx.x;
    const int wv = t >> 6, lane = t & 63;
    const int l15 = lane & 15, quad = lane >> 4;
    const long tile = blockIdx.x;
    const long p0 = tile * 64;
    const int bb = (int)(p0 >> 12);
    const int pl = (int)(p0 & 4095);

    const float* xr = x + (size_t)(p0 + wv * 16 + l15) * 256 + quad * 8;
    const unsigned short* BqH = wiF_h + (size_t)wv * 16384;
    const unsigned short* BqL = wiF_l + (size_t)wv * 16384;
    const unsigned short* BcH = wiF_h + (size_t)(4 + wv) * 16384;
    const unsigned short* BcL = wiF_l + (size_t)(4 + wv) * 16384;

    floatx4 accq[4][4], accc[4][4], gacc;
    #pragma unroll
    for (int im = 0; im < 4; ++im)
        #pragma unroll
        for (int in_ = 0; in_ < 4; ++in_) {
            accq[im][in_] = (floatx4){0.f, 0.f, 0.f, 0.f};
            accc[im][in_] = (floatx4){0.f, 0.f, 0.f, 0.f};
        }
    gacc = (floatx4){0.f, 0.f, 0.f, 0.f};

    #pragma unroll
    for (int h = 0; h < 2; ++h) {
        // ---- stage K-half h: thread (wv,lane) covers row p0+wv*16+l15 ----
        #pragma unroll
        for (int kk2 = 0; kk2 < 4; ++kk2) {
            const int kki = h * 4 + kk2;
            const float4 v0 = *(const float4*)&xr[kki * 32];
            const float4 v1 = *(const float4*)&xr[kki * 32 + 4];
            short8 hh, ll;
            unsigned short hs, ls;
            split2(v0.x, hs, ls); hh[0] = (short)hs; ll[0] = (short)ls;
            split2(v0.y, hs, ls); hh[1] = (short)hs; ll[1] = (short)ls;
            split2(v0.z, hs, ls); hh[2] = (short)hs; ll[2] = (short)ls;
            split2(v0.w, hs, ls); hh[3] = (short)hs; ll[3] = (short)ls;
            split2(v1.x, hs, ls); hh[4] = (short)hs; ll[4] = (short)ls;
            split2(v1.y, hs, ls); hh[5] = (short)hs; ll[5] = (short)ls;
            split2(v1.z, hs, ls); hh[6] = (short)hs; ll[6] = (short)ls;
            split2(v1.w, hs, ls); hh[7] = (short)hs; ll[7] = (short)ls;
            const int o = ((wv * 4 + kk2) * 64 + lane) * 8;
            *(short8*)&Ah[o] = hh;
            *(short8*)&Al[o] = ll;
        }
        __syncthreads();

        #pragma unroll
        for (int kk2 = 0; kk2 < 4; ++kk2) {
            const int kki = h * 4 + kk2;
            short8 ah[4], al[4], bh[4], bl[4];
            #pragma unroll
            for (int im = 0; im < 4; ++im) {
                const int o = ((im * 4 + kk2) * 64 + lane) * 8;
                ah[im] = *(const short8*)&Ah[o];
                al[im] = *(const short8*)&Al[o];
            }
            // q columns (g = wv)
            #pragma unroll
            for (int in_ = 0; in_ < 4; ++in_) {
                const int o = ((kki * 4 + in_) * 64 + lane) * 8;
                bh[in_] = *(const short8*)&BqH[o];
                bl[in_] = *(const short8*)&BqL[o];
            }
            #pragma unroll
            for (int im = 0; im < 4; ++im)
                #pragma unroll
                for (int in_ = 0; in_ < 4; ++in_) {
                    accq[im][in_] = __builtin_amdgcn_mfma_f32_16x16x32_bf16(ah[im], bh[in_], accq[im][in_], 0, 0, 0);
                    accq[im][in_] = __builtin_amdgcn_mfma_f32_16x16x32_bf16(ah[im], bl[in_], accq[im][in_], 0, 0, 0);
                    accq[im][in_] = __builtin_amdgcn_mfma_f32_16x16x32_bf16(al[im], bh[in_], accq[im][in_], 0, 0, 0);
                }
            // ctx columns (g = 4 + wv)
            #pragma unroll
            for (int in_ = 0; in_ < 4; ++in_) {
                const int o = ((kki * 4 + in_) * 64 + lane) * 8;
                bh[in_] = *(const short8*)&BcH[o];
                bl[in_] = *(const short8*)&BcL[o];
            }
            #pragma unroll
            for (int im = 0; im < 4; ++im)
                #pragma unroll
                for (int in_ = 0; in_ < 4; ++in_) {
                    accc[im][in_] = __builtin_amdgcn_mfma_f32_16x16x32_bf16(ah[im], bh[in_], accc[im][in_], 0, 0, 0);
                    accc[im][in_] = __builtin_amdgcn_mfma_f32_16x16x32_bf16(ah[im], bl[in_], accc[im][in_], 0, 0, 0);
                    accc[im][in_] = __builtin_amdgcn_mfma_f32_16x16x32_bf16(al[im], bh[in_], accc[im][in_], 0, 0, 0);
                }
            // gates (A rows im = wv; explicit re-load to avoid runtime index)
            {
                const int oga = ((wv * 4 + kk2) * 64 + lane) * 8;
                const short8 gah = *(const short8*)&Ah[oga];
                const short8 gal = *(const short8*)&Al[oga];
                const int ob = (kki * 64 + lane) * 8;
                const short8 gbh = *(const short8*)&wgF_h[ob];
                const short8 gbl = *(const short8*)&wgF_l[ob];
                gacc = __builtin_amdgcn_mfma_f32_16x16x32_bf16(gah, gbh, gacc, 0, 0, 0);
                gacc = __builtin_amdgcn_mfma_f32_16x16x32_bf16(gah, gbl, gacc, 0, 0, 0);
                gacc = __builtin_amdgcn_mfma_f32_16x16x32_bf16(gal, gbh, gacc, 0, 0, 0);
            }
        }
        if (h == 0) __syncthreads();
    }

    // ---- epilogues ----
    #pragma unroll
    for (int in_ = 0; in_ < 4; ++in_) {
        const int col = wv * 64 + in_ * 16 + l15;
        const float bi = b_init[col];
        #pragma unroll
        for (int im = 0; im < 4; ++im)
            #pragma unroll
            for (int r = 0; r < 4; ++r) {
                const int row = im * 16 + quad * 4 + r;
                qout[(p0 + row) * 256 + col] = accq[im][in_][r] + bi;
            }
    }
    #pragma unroll
    for (int in_ = 0; in_ < 4; ++in_) {
        const int col = wv * 64 + in_ * 16 + l15;     // channel
        const float bi = b_init[256 + col];
        #pragma unroll
        for (int im = 0; im < 4; ++im) {
            float4 o;
            o.x = accc[im][in_][0] + bi;
            o.y = accc[im][in_][1] + bi;
            o.z = accc[im][in_][2] + bi;
            o.w = accc[im][in_][3] + bi;
            *(float4*)&ctxp[((size_t)bb * 256 + col) * 4096 + pl + im * 16 + quad * 4] = o;
        }
    }
    if (l15 < 4) {
        const float bi = b_init[512 + l15];
        #pragma unroll
        for (int r = 0; r < 4; ++r) {
            const int row = wv * 16 + quad * 4 + r;
            gates[(p0 + row) * 4 + l15] = fminf(1.f, fmaxf(-1.f, gacc[r] + bi));
        }
    }
}

// ---------------------------------------------------------------------------
// conv_level: 4x2 output patch at (ry0,cx0) from LDS plane I (halo 4, pitch CP).
// Weights for this block's channel are uniform -> SGPRs. Returns GELU'd v[8].
// ---------------------------------------------------------------------------
template<int KS>
__device__ __forceinline__ void conv_level(const float* __restrict__ kwp,
                                           const float* __restrict__ I,
                                           int ry0, int cx0, float v[8]) {
    constexpr int P = KS / 2;
    constexpr int RWIN = 2 + 2 * P;
    float wk[KS * KS];
    #pragma unroll
    for (int i = 0; i < KS * KS; ++i) wk[i] = kwp[i * 256];

    float4 rb[RWIN][3];
    #pragma unroll
    for (int r = 0; r < 2 * P; ++r) {
        const int base = (ry0 + r - P + 4) * CP + cx0;
        rb[r][0] = *(const float4*)&I[base];
        rb[r][1] = *(const float4*)&I[base + 4];
        rb[r][2] = *(const float4*)&I[base + 8];
    }
    #pragma unroll
    for (int j = 0; j < 2; ++j) {
        {
            const int r = j + 2 * P;
            const int base = (ry0 + r - P + 4) * CP + cx0;
            rb[r][0] = *(const float4*)&I[base];
            rb[r][1] = *(const float4*)&I[base + 4];
            rb[r][2] = *(const float4*)&I[base + 8];
        }
        float s0 = 0.f, s1 = 0.f, s2 = 0.f, s3 = 0.f;
        #pragma unroll
        for (int dy = 0; dy < KS; ++dy) {
            const float* rw = (const float*)&rb[j + dy][0];   // 12 floats, cols cx0-4..cx0+7
            #pragma unroll
            for (int dx = 0; dx < KS; ++dx) {
                const float wgt = wk[dy * KS + dx];
                s0 += rw[4 - P + 0 + dx] * wgt;
                s1 += rw[4 - P + 1 + dx] * wgt;
                s2 += rw[4 - P + 2 + dx] * wgt;
                s3 += rw[4 - P + 3 + dx] * wgt;
            }
        }
        v[j * 4 + 0] = gelu_f(s0);
        v[j * 4 + 1] = gelu_f(s1);
        v[j * 4 + 2] = gelu_f(s2);
        v[j * 4 + 3] = gelu_f(s3);
    }
}

// ---------------------------------------------------------------------------
// k_conv_fused v2: 512 threads/block (4x2 patch/thread) -> 24 waves/CU at the
// same 44KB LDS, and py-groups land on distinct banks (2*CP%32=24).
// ---------------------------------------------------------------------------
__global__ __launch_bounds__(512) void k_conv_fused(const float* __restrict__ ctxp,
                                                    const float* __restrict__ k0,
                                                    const float* __restrict__ k1,
                                                    const float* __restrict__ k2,
                                                    const float* __restrict__ gates,
                                                    float* __restrict__ c_allp) {
    __shared__ float X[CROWS * CP];
    __shared__ float Y[CROWS * CP];
    const int t = threadIdx.x;
    const int bc = blockIdx.x;            // b*256 + c
    const int b = bc >> 8, c = bc & 255;
    const float* src = ctxp + (size_t)bc * 4096;

    for (int i = t; i < CROWS * CP; i += 512) { X[i] = 0.f; Y[i] = 0.f; }
    __syncthreads();
    #pragma unroll
    for (int i = 0; i < 2; ++i) {
        const int p = i * 2048 + t * 4;
        const float4 vv = *(const float4*)&src[p];
        *(float4*)&X[((p >> 6) + 4) * CP + (p & 63) + 4] = vv;
    }
    __syncthreads();

    const int px = t & 15, py = t >> 4;   // py 0..31
    const int cx0 = px * 4, ry0 = py * 2;
    const float* gbase = gates + (size_t)b * 4096 * 4;

    float acc[8], v[8];

    // level 0: 3x3 from X, write t1 -> Y
    conv_level<3>(k0 + c, X, ry0, cx0, v);
    #pragma unroll
    for (int j = 0; j < 2; ++j) {
        *(float4*)&Y[(ry0 + j + 4) * CP + cx0 + 4] = *(float4*)&v[j * 4];
        #pragma unroll
        for (int i2 = 0; i2 < 4; ++i2)
            acc[j * 4 + i2] = v[j * 4 + i2] * gbase[((ry0 + j) * 64 + cx0 + i2) * 4 + 0];
    }
    __syncthreads();

    // level 1: 5x5 from Y, write t2 -> X
    conv_level<5>(k1 + c, Y, ry0, cx0, v);
    #pragma unroll
    for (int j = 0; j < 2; ++j) {
        *(float4*)&X[(ry0 + j + 4) * CP + cx0 + 4] = *(float4*)&v[j * 4];
        #pragma unroll
        for (int i2 = 0; i2 < 4; ++i2)
            acc[j * 4 + i2] += v[j * 4 + i2] * gbase[((ry0 + j) * 64 + cx0 + i2) * 4 + 1];
    }
    __syncthreads();

    // level 2: 7x7 from X, t3 stays in registers
    conv_level<7>(k2 + c, X, ry0, cx0, v);
    float vsum = 0.f;
    #pragma unroll
    for (int j = 0; j < 2; ++j)
        #pragma unroll
        for (int i2 = 0; i2 < 4; ++i2) {
            acc[j * 4 + i2] += v[j * 4 + i2] * gbase[((ry0 + j) * 64 + cx0 + i2) * 4 + 2];
            vsum += v[j * 4 + i2];
        }

    // in-block mean of t3 -> tanh -> gl (X reused as scratch after barrier)
    __syncthreads();
    X[t] = vsum;
    __syncthreads();
    if (t < 64) {
        float s = 0.f;
        #pragma unroll
        for (int k = 0; k < 8; ++k) s += X[t + 64 * k];
        #pragma unroll
        for (int off = 32; off >= 1; off >>= 1)
            s += __shfl_down(s, off, 64);
        if (t == 0) X[0] = tanhf(s * (1.f / 4096.f));
    }
    __syncthreads();
    const float gl = X[0];

    float* dst = c_allp + (size_t)bc * 4096;
    #pragma unroll
    for (int j = 0; j < 2; ++j) {
        float4 o;
        o.x = acc[j * 4 + 0] + gl * gbase[((ry0 + j) * 64 + cx0 + 0) * 4 + 3];
        o.y = acc[j * 4 + 1] + gl * gbase[((ry0 + j) * 64 + cx0 + 1) * 4 + 3];
        o.z = acc[j * 4 + 2] + gl * gbase[((ry0 + j) * 64 + cx0 + 2) * 4 + 3];
        o.w = acc[j * 4 + 3] + gl * gbase[((ry0 + j) * 64 + cx0 + 3) * 4 + 3];
        *(float4*)&dst[(ry0 + j) * 64 + cx0] = o;
    }
}

// ---------------------------------------------------------------------------
// k_final_mfma: stage c_allp (planar -> LDS transpose, split bf16); GEMM1
// mod = c_all@w_mod; p = clip(q)*clip(mod+b_mod); GEMM2 out = p@w_proj+b_proj.
// qout aliases d_out (holds q on entry). B in fragment order; K-loops unrolled.
// ---------------------------------------------------------------------------
__global__ __launch_bounds__(256) void k_final_mfma(float* qout,
                                                    const float* __restrict__ c_allp,
                                                    const unsigned short* __restrict__ wmF_h,
                                                    const unsigned short* __restrict__ wmF_l,
                                                    const unsigned short* __restrict__ wpF_h,
                                                    const unsigned short* __restrict__ wpF_l,
                                                    const float* __restrict__ b_mod,
                                                    const float* __restrict__ b_proj) {
    __shared__ unsigned short Ah[64 * PITCH];
    __shared__ unsigned short Al[64 * PITCH];
    const int t = threadIdx.x;
    const long p0 = (long)blockIdx.x * 64;
    const int b = (int)(p0 >> 12);
    const int pl = (int)(p0 & 4095);

    // transpose-stage: thread t = channel t, 64 consecutive pixels
    {
        const float* src = c_allp + ((size_t)b * 256 + t) * 4096 + pl;
        #pragma unroll
        for (int i = 0; i < 16; ++i) {
            const float4 vv = *(const float4*)&src[i * 4];
            unsigned short h, l;
            split2(vv.x, h, l); Ah[(i*4+0)*PITCH + t] = h; Al[(i*4+0)*PITCH + t] = l;
            split2(vv.y, h, l); Ah[(i*4+1)*PITCH + t] = h; Al[(i*4+1)*PITCH + t] = l;
            split2(vv.z, h, l); Ah[(i*4+2)*PITCH + t] = h; Al[(i*4+2)*PITCH + t] = l;
            split2(vv.w, h, l); Ah[(i*4+3)*PITCH + t] = h; Al[(i*4+3)*PITCH + t] = l;
        }
    }
    __syncthreads();

    const int wv = t >> 6, lane = t & 63;
    const int l15 = lane & 15, quad = lane >> 4;
    const int ncol0 = wv * 64;
    const unsigned short* BmH = wmF_h + (size_t)wv * 16384;
    const unsigned short* BmL = wmF_l + (size_t)wv * 16384;
    const unsigned short* BpH = wpF_h + (size_t)wv * 16384;
    const unsigned short* BpL = wpF_l + (size_t)wv * 16384;

    floatx4 acc[4][4];
    #pragma unroll
    for (int im = 0; im < 4; ++im)
        #pragma unroll
        for (int in_ = 0; in_ < 4; ++in_)
            acc[im][in_] = (floatx4){0.f, 0.f, 0.f, 0.f};

    #pragma unroll
    for (int kki = 0; kki < 8; ++kki) {
        short8 ah[4], al[4], bh[4], bl[4];
        #pragma unroll
        for (int in_ = 0; in_ < 4; ++in_) {
            const int o = ((kki * 4 + in_) * 64 + lane) * 8;
            bh[in_] = *(const short8*)&BmH[o];
            bl[in_] = *(const short8*)&BmL[o];
        }
        #pragma unroll
        for (int im = 0; im < 4; ++im) {
            const int off = (im * 16 + l15) * PITCH + kki * 32 + quad * 8;
            ah[im] = *(const short8*)&Ah[off];
            al[im] = *(const short8*)&Al[off];
        }
        #pragma unroll
        for (int im = 0; im < 4; ++im)
            #pragma unroll
            for (int in_ = 0; in_ < 4; ++in_) {
                acc[im][in_] = __builtin_amdgcn_mfma_f32_16x16x32_bf16(ah[im], bh[in_], acc[im][in_], 0, 0, 0);
                acc[im][in_] = __builtin_amdgcn_mfma_f32_16x16x32_bf16(ah[im], bl[in_], acc[im][in_], 0, 0, 0);
                acc[im][in_] = __builtin_amdgcn_mfma_f32_16x16x32_bf16(al[im], bh[in_], acc[im][in_], 0, 0, 0);
            }
    }
    __syncthreads();

    // epilogue1: p = clip(q)*clip(mod + b_mod) -> LDS hi/lo
    #pragma unroll
    for (int in_ = 0; in_ < 4; ++in_) {
        const int col = ncol0 + in_ * 16 + l15;
        const float bm = b_mod[col];
        #pragma unroll
        for (int im = 0; im < 4; ++im)
            #pragma unroll
            for (int r = 0; r < 4; ++r) {
                const int row = im * 16 + quad * 4 + r;
                const float m = clip100(acc[im][in_][r] + bm);
                const float qv = clip100(qout[(p0 + row) * 256 + col]);
                unsigned short h, l;
                split2(qv * m, h, l);
                Ah[row * PITCH + col] = h;
                Al[row * PITCH + col] = l;
            }
    }
    __syncthreads();

    #pragma unroll
    for (int im = 0; im < 4; ++im)
        #pragma unroll
        for (int in_ = 0; in_ < 4; ++in_)
            acc[im][in_] = (floatx4){0.f, 0.f, 0.f, 0.f};

    #pragma unroll
    for (int kki = 0; kki < 8; ++kki) {
        short8 ah[4], al[4], bh[4], bl[4];
        #pragma unroll
        for (int in_ = 0; in_ < 4; ++in_) {
            const int o = ((kki * 4 + in_) * 64 + lane) * 8;
            bh[in_] = *(const short8*)&BpH[o];
            bl[in_] = *(const short8*)&BpL[o];
        }
        #pragma unroll
        for (int im = 0; im < 4; ++im) {
            const int off = (im * 16 + l15) * PITCH + kki * 32 + quad * 8;
            ah[im] = *(const short8*)&Ah[off];
            al[im] = *(const short8*)&Al[off];
        }
        #pragma unroll
        for (int im = 0; im < 4; ++im)
            #pragma unroll
            for (int in_ = 0; in_ < 4; ++in_) {
                acc[im][in_] = __builtin_amdgcn_mfma_f32_16x16x32_bf16(ah[im], bh[in_], acc[im][in_], 0, 0, 0);
                acc[im][in_] = __builtin_amdgcn_mfma_f32_16x16x32_bf16(ah[im], bl[in_], acc[im][in_], 0, 0, 0);
                acc[im][in_] = __builtin_amdgcn_mfma_f32_16x16x32_bf16(al[im], bh[in_], acc[im][in_], 0, 0, 0);
            }
    }

    #pragma unroll
    for (int in_ = 0; in_ < 4; ++in_) {
        const int col = ncol0 + in_ * 16 + l15;
        const float bp = b_proj[col];
        #pragma unroll
        for (int im = 0; im < 4; ++im)
            #pragma unroll
            for (int r = 0; r < 4; ++r) {
                const int row = im * 16 + quad * 4 + r;
                qout[(p0 + row) * 256 + col] = acc[im][in_][r] + bp;
            }
    }
}

// ---------------------------------------------------------------------------
extern "C" void kernel_launch(void* const* d_in, const int* in_sizes, int n_in,
                              void* d_out, int out_size, void* d_ws, size_t ws_size,
                              hipStream_t stream) {
    const float* x      = (const float*)d_in[0];
    const float* w_init = (const float*)d_in[1];
    const float* b_init = (const float*)d_in[2];
    const float* k0     = (const float*)d_in[3];
    const float* k1     = (const float*)d_in[4];
    const float* k2     = (const float*)d_in[5];
    const float* w_mod  = (const float*)d_in[6];
    const float* b_mod  = (const float*)d_in[7];
    const float* w_proj = (const float*)d_in[8];
    const float* b_proj = (const float*)d_in[9];
    float* qout = (float*)d_out;

    float* ws = (float*)d_ws;
    const long NP = (long)NPIX * DIMC;
    float* ctxp    = ws;                          // planar [b][c][4096]
    float* c_allp  = ws + NP;                     // planar [b][c][4096]
    float* gates   = ws + 2 * NP;                 // NPIX*4 floats
    unsigned short* wiF_h = (unsigned short*)(gates + (long)NPIX * 4);
    unsigned short* wiF_l = wiF_h + 512 * 256;
    unsigned short* wmF_h = wiF_l + 512 * 256;
    unsigned short* wmF_l = wmF_h + 256 * 256;
    unsigned short* wpF_h = wmF_l + 256 * 256;
    unsigned short* wpF_l = wpF_h + 256 * 256;
    unsigned short* wgF_h = wpF_l + 256 * 256;
    unsigned short* wgF_l = wgF_h + 16 * 256;

    k_prep<<<1040, 256, 0, stream>>>(w_init, w_mod, w_proj,
                                     wiF_h, wiF_l, wmF_h, wmF_l, wpF_h, wpF_l,
                                     wgF_h, wgF_l);
    k_init_mfma<<<NPIX / 64, 256, 0, stream>>>(x, wiF_h, wiF_l,
                                               wgF_h, wgF_l, b_init,
                                               qout, ctxp, gates);
    k_conv_fused<<<NB * 256, 512, 0, stream>>>(ctxp, k0, k1, k2, gates, c_allp);
    k_final_mfma<<<NPIX / 64, 256, 0, stream>>>(qout, c_allp,
                                                wmF_h, wmF_l, wpF_h, wpF_l,
                                                b_mod, b_proj);
}

// Round 5
// 836.656 us; speedup vs baseline: 1.4296x; 1.0350x over previous
//
#include <hip/hip_runtime.h>
#include <math.h>

#define DIMC 256
#define CO   516
#define NB   32
#define NH   64
#define NW   64
#define NPIX (NB*NH*NW)   // 131072
#define PITCH 264         // k_final LDS row pitch in shorts (256 + 8 pad)
#define CP    76          // conv LDS pitch (floats), %4==0
#define CROWS 72          // 64 + 2*4 halo

typedef short short8 __attribute__((ext_vector_type(8)));
typedef float floatx4 __attribute__((ext_vector_type(4)));

__device__ __forceinline__ float gelu_f(float x) {
    return 0.5f * x * (1.0f + erff(x * 0.7071067811865476f));
}
__device__ __forceinline__ float clip100(float v) {
    return fminf(100.f, fmaxf(-100.f, v));
}
// round-to-nearest-even split of fp32 into bf16 hi + bf16 lo (x ~= hi+lo)
__device__ __forceinline__ void split2(float x, unsigned short& h, unsigned short& l) {
    unsigned int xb = __float_as_uint(x);
    unsigned int hb = (xb + 0x7fffu + ((xb >> 16) & 1u)) & 0xffff0000u;
    h = (unsigned short)(hb >> 16);
    float r = x - __uint_as_float(hb);
    unsigned int rb = __float_as_uint(r);
    l = (unsigned short)((rb + 0x7fffu + ((rb >> 16) & 1u)) >> 16);
}

// ---------------------------------------------------------------------------
// Weight prep -> FRAGMENT-ORDER bf16 hi/lo.
// Fragment layout: frag (g,kki,in_) holds B[k = kki*32+quad*8+j][col = g*64+in_*16+l15]
// at ((fragIdx)*64 + lane)*8 + j, lane = quad*16+l15.
// ---------------------------------------------------------------------------
__global__ __launch_bounds__(256) void k_prep(const float* __restrict__ w_init,
                                              const float* __restrict__ w_mod,
                                              const float* __restrict__ w_proj,
                                              unsigned short* wiF_h, unsigned short* wiF_l,
                                              unsigned short* wmF_h, unsigned short* wmF_l,
                                              unsigned short* wpF_h, unsigned short* wpF_l,
                                              unsigned short* wgF_h, unsigned short* wgF_l) {
    const int n = blockIdx.x;
    const int k = threadIdx.x;
    const int kki = k >> 5, quad = (k >> 3) & 3, j = k & 7;
    unsigned short h, l;
    if (n < 1024) {
        const int nn = (n < 512) ? n : (n < 768 ? n - 512 : n - 768);
        const int g = nn >> 6, in_ = (nn >> 4) & 3, l15 = nn & 15;
        const size_t idx = ((size_t)((g * 8 + kki) * 4 + in_) * 64 + quad * 16 + l15) * 8 + j;
        if (n < 512) {
            split2(w_init[k * CO + n], h, l);
            wiF_h[idx] = h; wiF_l[idx] = l;
        } else if (n < 768) {
            split2(w_mod[k * 256 + nn], h, l);
            wmF_h[idx] = h; wmF_l[idx] = l;
        } else {
            split2(w_proj[k * 256 + nn], h, l);
            wpF_h[idx] = h; wpF_l[idx] = l;
        }
    } else {
        const int nn = n - 1024;          // 0..15 = l15 of padded gate tile
        const float v = (nn < 4) ? w_init[k * CO + 512 + nn] : 0.f;
        split2(v, h, l);
        const size_t idx = ((size_t)kki * 64 + quad * 16 + nn) * 8 + j;
        wgF_h[idx] = h; wgF_l[idx] = l;
    }
}

// ---------------------------------------------------------------------------
// k_init_mfma v4: K-tiled LDS staging (32KB). gates now written PLANAR
// [b][lvl][4096] so k_conv can vector-load them.
// ---------------------------------------------------------------------------
__global__ __launch_bounds__(256) void k_init_mfma(const float* __restrict__ x,
                                                   const unsigned short* __restrict__ wiF_h,
                                                   const unsigned short* __restrict__ wiF_l,
                                                   const unsigned short* __restrict__ wgF_h,
                                                   const unsigned short* __restrict__ wgF_l,
                                                   const float* __restrict__ b_init,
                                                   float* __restrict__ qout,
                                                   float* __restrict__ ctxp,
                                                   float* __restrict__ gatesp) {
    __shared__ unsigned short Ah[8192];   // 16 frags * 64 lanes * 8 shorts = 16KB
    __shared__ unsigned short Al[8192];
    const int t = threadIdx.x;
    const int wv = t >> 6, lane = t & 63;
    const int l15 = lane & 15, quad = lane >> 4;
    const long tile = blockIdx.x;
    const long p0 = tile * 64;
    const int bb = (int)(p0 >> 12);
    const int pl = (int)(p0 & 4095);

    const float* xr = x + (size_t)(p0 + wv * 16 + l15) * 256 + quad * 8;
    const unsigned short* BqH = wiF_h + (size_t)wv * 16384;
    const unsigned short* BqL = wiF_l + (size_t)wv * 16384;
    const unsigned short* BcH = wiF_h + (size_t)(4 + wv) * 16384;
    const unsigned short* BcL = wiF_l + (size_t)(4 + wv) * 16384;

    floatx4 accq[4][4], accc[4][4], gacc;
    #pragma unroll
    for (int im = 0; im < 4; ++im)
        #pragma unroll
        for (int in_ = 0; in_ < 4; ++in_) {
            accq[im][in_] = (floatx4){0.f, 0.f, 0.f, 0.f};
            accc[im][in_] = (floatx4){0.f, 0.f, 0.f, 0.f};
        }
    gacc = (floatx4){0.f, 0.f, 0.f, 0.f};

    #pragma unroll
    for (int h = 0; h < 2; ++h) {
        #pragma unroll
        for (int kk2 = 0; kk2 < 4; ++kk2) {
            const int kki = h * 4 + kk2;
            const float4 v0 = *(const float4*)&xr[kki * 32];
            const float4 v1 = *(const float4*)&xr[kki * 32 + 4];
            short8 hh, ll;
            unsigned short hs, ls;
            split2(v0.x, hs, ls); hh[0] = (short)hs; ll[0] = (short)ls;
            split2(v0.y, hs, ls); hh[1] = (short)hs; ll[1] = (short)ls;
            split2(v0.z, hs, ls); hh[2] = (short)hs; ll[2] = (short)ls;
            split2(v0.w, hs, ls); hh[3] = (short)hs; ll[3] = (short)ls;
            split2(v1.x, hs, ls); hh[4] = (short)hs; ll[4] = (short)ls;
            split2(v1.y, hs, ls); hh[5] = (short)hs; ll[5] = (short)ls;
            split2(v1.z, hs, ls); hh[6] = (short)hs; ll[6] = (short)ls;
            split2(v1.w, hs, ls); hh[7] = (short)hs; ll[7] = (short)ls;
            const int o = ((wv * 4 + kk2) * 64 + lane) * 8;
            *(short8*)&Ah[o] = hh;
            *(short8*)&Al[o] = ll;
        }
        __syncthreads();

        #pragma unroll
        for (int kk2 = 0; kk2 < 4; ++kk2) {
            const int kki = h * 4 + kk2;
            short8 ah[4], al[4], bh[4], bl[4];
            #pragma unroll
            for (int im = 0; im < 4; ++im) {
                const int o = ((im * 4 + kk2) * 64 + lane) * 8;
                ah[im] = *(const short8*)&Ah[o];
                al[im] = *(const short8*)&Al[o];
            }
            // q columns (g = wv)
            #pragma unroll
            for (int in_ = 0; in_ < 4; ++in_) {
                const int o = ((kki * 4 + in_) * 64 + lane) * 8;
                bh[in_] = *(const short8*)&BqH[o];
                bl[in_] = *(const short8*)&BqL[o];
            }
            #pragma unroll
            for (int im = 0; im < 4; ++im)
                #pragma unroll
                for (int in_ = 0; in_ < 4; ++in_) {
                    accq[im][in_] = __builtin_amdgcn_mfma_f32_16x16x32_bf16(ah[im], bh[in_], accq[im][in_], 0, 0, 0);
                    accq[im][in_] = __builtin_amdgcn_mfma_f32_16x16x32_bf16(ah[im], bl[in_], accq[im][in_], 0, 0, 0);
                    accq[im][in_] = __builtin_amdgcn_mfma_f32_16x16x32_bf16(al[im], bh[in_], accq[im][in_], 0, 0, 0);
                }
            // ctx columns (g = 4 + wv)
            #pragma unroll
            for (int in_ = 0; in_ < 4; ++in_) {
                const int o = ((kki * 4 + in_) * 64 + lane) * 8;
                bh[in_] = *(const short8*)&BcH[o];
                bl[in_] = *(const short8*)&BcL[o];
            }
            #pragma unroll
            for (int im = 0; im < 4; ++im)
                #pragma unroll
                for (int in_ = 0; in_ < 4; ++in_) {
                    accc[im][in_] = __builtin_amdgcn_mfma_f32_16x16x32_bf16(ah[im], bh[in_], accc[im][in_], 0, 0, 0);
                    accc[im][in_] = __builtin_amdgcn_mfma_f32_16x16x32_bf16(ah[im], bl[in_], accc[im][in_], 0, 0, 0);
                    accc[im][in_] = __builtin_amdgcn_mfma_f32_16x16x32_bf16(al[im], bh[in_], accc[im][in_], 0, 0, 0);
                }
            // gates (A rows im = wv)
            {
                const int oga = ((wv * 4 + kk2) * 64 + lane) * 8;
                const short8 gah = *(const short8*)&Ah[oga];
                const short8 gal = *(const short8*)&Al[oga];
                const int ob = (kki * 64 + lane) * 8;
                const short8 gbh = *(const short8*)&wgF_h[ob];
                const short8 gbl = *(const short8*)&wgF_l[ob];
                gacc = __builtin_amdgcn_mfma_f32_16x16x32_bf16(gah, gbh, gacc, 0, 0, 0);
                gacc = __builtin_amdgcn_mfma_f32_16x16x32_bf16(gah, gbl, gacc, 0, 0, 0);
                gacc = __builtin_amdgcn_mfma_f32_16x16x32_bf16(gal, gbh, gacc, 0, 0, 0);
            }
        }
        if (h == 0) __syncthreads();
    }

    // ---- epilogues ----
    #pragma unroll
    for (int in_ = 0; in_ < 4; ++in_) {
        const int col = wv * 64 + in_ * 16 + l15;
        const float bi = b_init[col];
        #pragma unroll
        for (int im = 0; im < 4; ++im)
            #pragma unroll
            for (int r = 0; r < 4; ++r) {
                const int row = im * 16 + quad * 4 + r;
                qout[(p0 + row) * 256 + col] = accq[im][in_][r] + bi;
            }
    }
    #pragma unroll
    for (int in_ = 0; in_ < 4; ++in_) {
        const int col = wv * 64 + in_ * 16 + l15;     // channel
        const float bi = b_init[256 + col];
        #pragma unroll
        for (int im = 0; im < 4; ++im) {
            float4 o;
            o.x = accc[im][in_][0] + bi;
            o.y = accc[im][in_][1] + bi;
            o.z = accc[im][in_][2] + bi;
            o.w = accc[im][in_][3] + bi;
            *(float4*)&ctxp[((size_t)bb * 256 + col) * 4096 + pl + im * 16 + quad * 4] = o;
        }
    }
    if (l15 < 4) {
        const float bi = b_init[512 + l15];
        // planar gates: [b][lvl=l15][pixel]
        #pragma unroll
        for (int r = 0; r < 4; ++r) {
            const int row = wv * 16 + quad * 4 + r;
            gatesp[((size_t)bb * 4 + l15) * 4096 + pl + row] =
                fminf(1.f, fmaxf(-1.f, gacc[r] + bi));
        }
    }
}

// ---------------------------------------------------------------------------
// conv_level v2: row-streaming, register-bounded (<= ~24 live floats).
// 4x2 output patch at (ry0,cx0) from LDS plane I (halo 4, pitch CP).
// Each input row is loaded once (3x float4) and applied to both output rows.
// ---------------------------------------------------------------------------
template<int KS>
__device__ __forceinline__ void conv_level(const float* __restrict__ kwp,
                                           const float* __restrict__ I,
                                           int ry0, int cx0, float v[8]) {
    constexpr int P = KS / 2;
    float a0[4] = {0.f, 0.f, 0.f, 0.f};
    float a1[4] = {0.f, 0.f, 0.f, 0.f};
    #pragma unroll
    for (int r = 0; r < 2 * P + 2; ++r) {          // input row = ry0 + r - P
        const int base = (ry0 + r - P + 4) * CP + cx0;
        const float4 w0 = *(const float4*)&I[base];
        const float4 w1 = *(const float4*)&I[base + 4];
        const float4 w2 = *(const float4*)&I[base + 8];
        float rw[12] = {w0.x, w0.y, w0.z, w0.w,
                        w1.x, w1.y, w1.z, w1.w,
                        w2.x, w2.y, w2.z, w2.w};
        if (r <= 2 * P) {                          // output row j=0, dy=r
            #pragma unroll
            for (int dx = 0; dx < KS; ++dx) {
                const float wg = kwp[(r * KS + dx) * 256];
                a0[0] += rw[4 - P + 0 + dx] * wg;
                a0[1] += rw[4 - P + 1 + dx] * wg;
                a0[2] += rw[4 - P + 2 + dx] * wg;
                a0[3] += rw[4 - P + 3 + dx] * wg;
            }
        }
        if (r >= 1) {                              // output row j=1, dy=r-1
            #pragma unroll
            for (int dx = 0; dx < KS; ++dx) {
                const float wg = kwp[((r - 1) * KS + dx) * 256];
                a1[0] += rw[4 - P + 0 + dx] * wg;
                a1[1] += rw[4 - P + 1 + dx] * wg;
                a1[2] += rw[4 - P + 2 + dx] * wg;
                a1[3] += rw[4 - P + 3 + dx] * wg;
            }
        }
    }
    v[0] = gelu_f(a0[0]); v[1] = gelu_f(a0[1]); v[2] = gelu_f(a0[2]); v[3] = gelu_f(a0[3]);
    v[4] = gelu_f(a1[0]); v[5] = gelu_f(a1[1]); v[6] = gelu_f(a1[2]); v[7] = gelu_f(a1[3]);
}

// ---------------------------------------------------------------------------
// k_conv_fused v3: 512 threads (4x2 patch/thread); planar gate float4 loads;
// halo-only zeroing; separate scratch S for the mean-reduce (one less barrier).
// ---------------------------------------------------------------------------
__global__ __launch_bounds__(512) void k_conv_fused(const float* __restrict__ ctxp,
                                                    const float* __restrict__ k0,
                                                    const float* __restrict__ k1,
                                                    const float* __restrict__ k2,
                                                    const float* __restrict__ gatesp,
                                                    float* __restrict__ c_allp) {
    __shared__ float X[CROWS * CP];
    __shared__ float Y[CROWS * CP];
    __shared__ float S[512];
    const int t = threadIdx.x;
    const int bc = blockIdx.x;            // b*256 + c
    const int b = bc >> 8, c = bc & 255;
    const float* src = ctxp + (size_t)bc * 4096;

    // halo-only zeroing: rows 0..3 & 68..71 full; rows 4..67 cols {0..3, 68..75}
    for (int i = t; i < 4 * CP; i += 512) {
        X[i] = 0.f; X[68 * CP + i] = 0.f;
        Y[i] = 0.f; Y[68 * CP + i] = 0.f;
    }
    for (int i = t; i < 64 * 12; i += 512) {
        const int r = i / 12, cc = i % 12;
        const int off = (r + 4) * CP + (cc < 4 ? cc : cc + 64);
        X[off] = 0.f; Y[off] = 0.f;
    }
    __syncthreads();
    #pragma unroll
    for (int i = 0; i < 2; ++i) {
        const int p = i * 2048 + t * 4;
        const float4 vv = *(const float4*)&src[p];
        *(float4*)&X[((p >> 6) + 4) * CP + (p & 63) + 4] = vv;
    }
    __syncthreads();

    const int px = t & 15, py = t >> 4;   // py 0..31
    const int cx0 = px * 4, ry0 = py * 2;
    const float* gp0 = gatesp + ((size_t)b * 4 + 0) * 4096;
    const float* gp1 = gatesp + ((size_t)b * 4 + 1) * 4096;
    const float* gp2 = gatesp + ((size_t)b * 4 + 2) * 4096;
    const float* gp3 = gatesp + ((size_t)b * 4 + 3) * 4096;

    float acc[8], v[8];

    // level 0: 3x3 from X, write t1 -> Y
    {
        const float4 ga = *(const float4*)&gp0[(ry0 + 0) * 64 + cx0];
        const float4 gb = *(const float4*)&gp0[(ry0 + 1) * 64 + cx0];
        conv_level<3>(k0 + c, X, ry0, cx0, v);
        *(float4*)&Y[(ry0 + 4) * CP + cx0 + 4] = *(float4*)&v[0];
        *(float4*)&Y[(ry0 + 5) * CP + cx0 + 4] = *(float4*)&v[4];
        acc[0] = v[0] * ga.x; acc[1] = v[1] * ga.y; acc[2] = v[2] * ga.z; acc[3] = v[3] * ga.w;
        acc[4] = v[4] * gb.x; acc[5] = v[5] * gb.y; acc[6] = v[6] * gb.z; acc[7] = v[7] * gb.w;
    }
    __syncthreads();

    // level 1: 5x5 from Y, write t2 -> X
    {
        const float4 ga = *(const float4*)&gp1[(ry0 + 0) * 64 + cx0];
        const float4 gb = *(const float4*)&gp1[(ry0 + 1) * 64 + cx0];
        conv_level<5>(k1 + c, Y, ry0, cx0, v);
        *(float4*)&X[(ry0 + 4) * CP + cx0 + 4] = *(float4*)&v[0];
        *(float4*)&X[(ry0 + 5) * CP + cx0 + 4] = *(float4*)&v[4];
        acc[0] += v[0] * ga.x; acc[1] += v[1] * ga.y; acc[2] += v[2] * ga.z; acc[3] += v[3] * ga.w;
        acc[4] += v[4] * gb.x; acc[5] += v[5] * gb.y; acc[6] += v[6] * gb.z; acc[7] += v[7] * gb.w;
    }
    __syncthreads();

    // level 2: 7x7 from X, t3 stays in registers
    float vsum;
    {
        const float4 ga = *(const float4*)&gp2[(ry0 + 0) * 64 + cx0];
        const float4 gb = *(const float4*)&gp2[(ry0 + 1) * 64 + cx0];
        conv_level<7>(k2 + c, X, ry0, cx0, v);
        acc[0] += v[0] * ga.x; acc[1] += v[1] * ga.y; acc[2] += v[2] * ga.z; acc[3] += v[3] * ga.w;
        acc[4] += v[4] * gb.x; acc[5] += v[5] * gb.y; acc[6] += v[6] * gb.z; acc[7] += v[7] * gb.w;
        vsum = v[0] + v[1] + v[2] + v[3] + v[4] + v[5] + v[6] + v[7];
    }

    // in-block mean of t3 -> tanh -> gl (separate scratch, no extra barrier)
    S[t] = vsum;
    __syncthreads();
    if (t < 64) {
        float s = 0.f;
        #pragma unroll
        for (int k = 0; k < 8; ++k) s += S[t + 64 * k];
        #pragma unroll
        for (int off = 32; off >= 1; off >>= 1)
            s += __shfl_down(s, off, 64);
        if (t == 0) S[0] = tanhf(s * (1.f / 4096.f));
    }
    __syncthreads();
    const float gl = S[0];

    float* dst = c_allp + (size_t)bc * 4096;
    {
        const float4 ga = *(const float4*)&gp3[(ry0 + 0) * 64 + cx0];
        const float4 gb = *(const float4*)&gp3[(ry0 + 1) * 64 + cx0];
        float4 o0, o1;
        o0.x = acc[0] + gl * ga.x; o0.y = acc[1] + gl * ga.y;
        o0.z = acc[2] + gl * ga.z; o0.w = acc[3] + gl * ga.w;
        o1.x = acc[4] + gl * gb.x; o1.y = acc[5] + gl * gb.y;
        o1.z = acc[6] + gl * gb.z; o1.w = acc[7] + gl * gb.w;
        *(float4*)&dst[(ry0 + 0) * 64 + cx0] = o0;
        *(float4*)&dst[(ry0 + 1) * 64 + cx0] = o1;
    }
}

// ---------------------------------------------------------------------------
// k_final_mfma: stage c_allp (planar -> LDS transpose, split bf16); GEMM1
// mod = c_all@w_mod; p = clip(q)*clip(mod+b_mod); GEMM2 out = p@w_proj+b_proj.
// qout aliases d_out (holds q on entry). B in fragment order; K-loops unrolled.
// ---------------------------------------------------------------------------
__global__ __launch_bounds__(256) void k_final_mfma(float* qout,
                                                    const float* __restrict__ c_allp,
                                                    const unsigned short* __restrict__ wmF_h,
                                                    const unsigned short* __restrict__ wmF_l,
                                                    const unsigned short* __restrict__ wpF_h,
                                                    const unsigned short* __restrict__ wpF_l,
                                                    const float* __restrict__ b_mod,
                                                    const float* __restrict__ b_proj) {
    __shared__ unsigned short Ah[64 * PITCH];
    __shared__ unsigned short Al[64 * PITCH];
    const int t = threadIdx.x;
    const long p0 = (long)blockIdx.x * 64;
    const int b = (int)(p0 >> 12);
    const int pl = (int)(p0 & 4095);

    // transpose-stage: thread t = channel t, 64 consecutive pixels
    {
        const float* src = c_allp + ((size_t)b * 256 + t) * 4096 + pl;
        #pragma unroll
        for (int i = 0; i < 16; ++i) {
            const float4 vv = *(const float4*)&src[i * 4];
            unsigned short h, l;
            split2(vv.x, h, l); Ah[(i*4+0)*PITCH + t] = h; Al[(i*4+0)*PITCH + t] = l;
            split2(vv.y, h, l); Ah[(i*4+1)*PITCH + t] = h; Al[(i*4+1)*PITCH + t] = l;
            split2(vv.z, h, l); Ah[(i*4+2)*PITCH + t] = h; Al[(i*4+2)*PITCH + t] = l;
            split2(vv.w, h, l); Ah[(i*4+3)*PITCH + t] = h; Al[(i*4+3)*PITCH + t] = l;
        }
    }
    __syncthreads();

    const int wv = t >> 6, lane = t & 63;
    const int l15 = lane & 15, quad = lane >> 4;
    const int ncol0 = wv * 64;
    const unsigned short* BmH = wmF_h + (size_t)wv * 16384;
    const unsigned short* BmL = wmF_l + (size_t)wv * 16384;
    const unsigned short* BpH = wpF_h + (size_t)wv * 16384;
    const unsigned short* BpL = wpF_l + (size_t)wv * 16384;

    floatx4 acc[4][4];
    #pragma unroll
    for (int im = 0; im < 4; ++im)
        #pragma unroll
        for (int in_ = 0; in_ < 4; ++in_)
            acc[im][in_] = (floatx4){0.f, 0.f, 0.f, 0.f};

    #pragma unroll
    for (int kki = 0; kki < 8; ++kki) {
        short8 ah[4], al[4], bh[4], bl[4];
        #pragma unroll
        for (int in_ = 0; in_ < 4; ++in_) {
            const int o = ((kki * 4 + in_) * 64 + lane) * 8;
            bh[in_] = *(const short8*)&BmH[o];
            bl[in_] = *(const short8*)&BmL[o];
        }
        #pragma unroll
        for (int im = 0; im < 4; ++im) {
            const int off = (im * 16 + l15) * PITCH + kki * 32 + quad * 8;
            ah[im] = *(const short8*)&Ah[off];
            al[im] = *(const short8*)&Al[off];
        }
        #pragma unroll
        for (int im = 0; im < 4; ++im)
            #pragma unroll
            for (int in_ = 0; in_ < 4; ++in_) {
                acc[im][in_] = __builtin_amdgcn_mfma_f32_16x16x32_bf16(ah[im], bh[in_], acc[im][in_], 0, 0, 0);
                acc[im][in_] = __builtin_amdgcn_mfma_f32_16x16x32_bf16(ah[im], bl[in_], acc[im][in_], 0, 0, 0);
                acc[im][in_] = __builtin_amdgcn_mfma_f32_16x16x32_bf16(al[im], bh[in_], acc[im][in_], 0, 0, 0);
            }
    }
    __syncthreads();

    // epilogue1: p = clip(q)*clip(mod + b_mod) -> LDS hi/lo
    #pragma unroll
    for (int in_ = 0; in_ < 4; ++in_) {
        const int col = ncol0 + in_ * 16 + l15;
        const float bm = b_mod[col];
        #pragma unroll
        for (int im = 0; im < 4; ++im)
            #pragma unroll
            for (int r = 0; r < 4; ++r) {
                const int row = im * 16 + quad * 4 + r;
                const float m = clip100(acc[im][in_][r] + bm);
                const float qv = clip100(qout[(p0 + row) * 256 + col]);
                unsigned short h, l;
                split2(qv * m, h, l);
                Ah[row * PITCH + col] = h;
                Al[row * PITCH + col] = l;
            }
    }
    __syncthreads();

    #pragma unroll
    for (int im = 0; im < 4; ++im)
        #pragma unroll
        for (int in_ = 0; in_ < 4; ++in_)
            acc[im][in_] = (floatx4){0.f, 0.f, 0.f, 0.f};

    #pragma unroll
    for (int kki = 0; kki < 8; ++kki) {
        short8 ah[4], al[4], bh[4], bl[4];
        #pragma unroll
        for (int in_ = 0; in_ < 4; ++in_) {
            const int o = ((kki * 4 + in_) * 64 + lane) * 8;
            bh[in_] = *(const short8*)&BpH[o];
            bl[in_] = *(const short8*)&BpL[o];
        }
        #pragma unroll
        for (int im = 0; im < 4; ++im) {
            const int off = (im * 16 + l15) * PITCH + kki * 32 + quad * 8;
            ah[im] = *(const short8*)&Ah[off];
            al[im] = *(const short8*)&Al[off];
        }
        #pragma unroll
        for (int im = 0; im < 4; ++im)
            #pragma unroll
            for (int in_ = 0; in_ < 4; ++in_) {
                acc[im][in_] = __builtin_amdgcn_mfma_f32_16x16x32_bf16(ah[im], bh[in_], acc[im][in_], 0, 0, 0);
                acc[im][in_] = __builtin_amdgcn_mfma_f32_16x16x32_bf16(ah[im], bl[in_], acc[im][in_], 0, 0, 0);
                acc[im][in_] = __builtin_amdgcn_mfma_f32_16x16x32_bf16(al[im], bh[in_], acc[im][in_], 0, 0, 0);
            }
    }

    #pragma unroll
    for (int in_ = 0; in_ < 4; ++in_) {
        const int col = ncol0 + in_ * 16 + l15;
        const float bp = b_proj[col];
        #pragma unroll
        for (int im = 0; im < 4; ++im)
            #pragma unroll
            for (int r = 0; r < 4; ++r) {
                const int row = im * 16 + quad * 4 + r;
                qout[(p0 + row) * 256 + col] = acc[im][in_][r] + bp;
            }
    }
}

// ---------------------------------------------------------------------------
extern "C" void kernel_launch(void* const* d_in, const int* in_sizes, int n_in,
                              void* d_out, int out_size, void* d_ws, size_t ws_size,
                              hipStream_t stream) {
    const float* x      = (const float*)d_in[0];
    const float* w_init = (const float*)d_in[1];
    const float* b_init = (const float*)d_in[2];
    const float* k0     = (const float*)d_in[3];
    const float* k1     = (const float*)d_in[4];
    const float* k2     = (const float*)d_in[5];
    const float* w_mod  = (const float*)d_in[6];
    const float* b_mod  = (const float*)d_in[7];
    const float* w_proj = (const float*)d_in[8];
    const float* b_proj = (const float*)d_in[9];
    float* qout = (float*)d_out;

    float* ws = (float*)d_ws;
    const long NP = (long)NPIX * DIMC;
    float* ctxp    = ws;                          // planar [b][c][4096]
    float* c_allp  = ws + NP;                     // planar [b][c][4096]
    float* gatesp  = ws + 2 * NP;                 // planar [b][lvl][4096]
    unsigned short* wiF_h = (unsigned short*)(gatesp + (long)NPIX * 4);
    unsigned short* wiF_l = wiF_h + 512 * 256;
    unsigned short* wmF_h = wiF_l + 512 * 256;
    unsigned short* wmF_l = wmF_h + 256 * 256;
    unsigned short* wpF_h = wmF_l + 256 * 256;
    unsigned short* wpF_l = wpF_h + 256 * 256;
    unsigned short* wgF_h = wpF_l + 256 * 256;
    unsigned short* wgF_l = wgF_h + 16 * 256;

    k_prep<<<1040, 256, 0, stream>>>(w_init, w_mod, w_proj,
                                     wiF_h, wiF_l, wmF_h, wmF_l, wpF_h, wpF_l,
                                     wgF_h, wgF_l);
    k_init_mfma<<<NPIX / 64, 256, 0, stream>>>(x, wiF_h, wiF_l,
                                               wgF_h, wgF_l, b_init,
                                               qout, ctxp, gatesp);
    k_conv_fused<<<NB * 256, 512, 0, stream>>>(ctxp, k0, k1, k2, gatesp, c_allp);
    k_final_mfma<<<NPIX / 64, 256, 0, stream>>>(qout, c_allp,
                                                wmF_h, wmF_l, wpF_h, wpF_l,
                                                b_mod, b_proj);
}